// Round 1
// 3318.462 us; speedup vs baseline: 1.4827x; 1.4827x over previous
//
#include <hip/hip_runtime.h>
#include <math.h>

// B=8, C=128, H=128, W=128, D_INNER=256, D_STATE=64, HEADDIM=32, NHEADS=8,
// D_CONV=4, GN_GROUPS=8, D_XBC=384, D_INPROJ=648.
// Inputs f32 (probed via gn_g word0). OUTPUT IS F32 (reference output dtype).
// d_out = [out_2d: 16,777,216 f32][offset: 131,072 f32].
// h1 (f32) is staged in d_out's out_2d region (written by dwconv, read by gn_off,
// later fully overwritten by gemm2).

__device__ __forceinline__ float b2f(unsigned short u) {
  return __uint_as_float(((unsigned int)u) << 16);
}
__device__ __forceinline__ unsigned short f2b(float f) {
  unsigned int u = __float_as_uint(f);
  unsigned int r = (u + 0x7FFFu + ((u >> 16) & 1u)) >> 16;  // RNE
  return (unsigned short)r;
}
__device__ __forceinline__ bool in_is_f32(const void* gng) {
  return ((const unsigned int*)gng)[0] == 0x3F800000u;
}

#define P_DWW 0
#define P_CW 3200
#define P_CB 4736
#define P_GNG 5120
#define P_GNB 5248
#define P_PWW 5376
#define P_PWB 5504
#define P_DTB 5505
#define P_ALOG 5513
#define P_DSKIP 5521
#define P_NG 5529

__global__ void k_prep_params(const void* dww, const void* cw, const void* cb,
                              const void* gng, const void* gnb, const void* pww,
                              const void* pwb, const void* dtbias, const void* alog,
                              const void* dskip, const void* ng, float* __restrict__ P,
                              float* __restrict__ gst) {
  bool f = in_is_f32(gng);
  int tid = threadIdx.x;
  if (tid < 128) gst[tid] = 0.f;
  auto cvt = [&](const void* src, int n, int off) {
    for (int i = tid; i < n; i += 256)
      P[off + i] = f ? ((const float*)src)[i] : b2f(((const unsigned short*)src)[i]);
  };
  cvt(dww, 3200, P_DWW);
  cvt(cw, 1536, P_CW);
  cvt(cb, 384, P_CB);
  cvt(gng, 128, P_GNG);
  cvt(gnb, 128, P_GNB);
  cvt(pww, 128, P_PWW);
  cvt(pwb, 1, P_PWB);
  cvt(dtbias, 8, P_DTB);
  cvt(alog, 8, P_ALOG);
  cvt(dskip, 8, P_DSKIP);
  cvt(ng, 256, P_NG);
}

__global__ void k_prep_w(const void* wproj, const void* outw, const void* gng,
                         float* __restrict__ wprojf, float* __restrict__ outwf) {
  bool f = in_is_f32(gng);
  int stride = gridDim.x * blockDim.x;
  for (int i = blockIdx.x * blockDim.x + threadIdx.x; i < 82944; i += stride)
    wprojf[i] = f ? ((const float*)wproj)[i] : b2f(((const unsigned short*)wproj)[i]);
  for (int i = blockIdx.x * blockDim.x + threadIdx.x; i < 32768; i += stride)
    outwf[i] = f ? ((const float*)outw)[i] : b2f(((const unsigned short*)outw)[i]);
}

// ---------------- K1: depthwise 5x5 conv (SAME, zero pad) + group stats ----------
// x staged in LDS as bf16 (f32 tile would exceed 64KB static LDS); h1 out f32.
__global__ __launch_bounds__(256) void k_dwconv(const void* __restrict__ x,
                                                const void* __restrict__ gng,
                                                const float* __restrict__ P,
                                                float* __restrict__ h1,
                                                float* __restrict__ gst) {
  int bc = blockIdx.x;
  int b = bc >> 7, c = bc & 127;
  bool f32x = in_is_f32(gng);
  __shared__ unsigned short t[132 * 132];
  __shared__ float red[8];
  for (int i = threadIdx.x; i < 132 * 132; i += 256) t[i] = 0;
  __syncthreads();
  const float* xf = (const float*)x + (size_t)bc * 16384;
  const unsigned short* xb = (const unsigned short*)x + (size_t)bc * 16384;
  for (int i = threadIdx.x; i < 16384; i += 256) {
    int y = i >> 7, xw = i & 127;
    t[(y + 2) * 132 + xw + 2] = f32x ? f2b(xf[i]) : xb[i];
  }
  float w[25];
#pragma unroll
  for (int k = 0; k < 25; ++k) w[k] = P[P_DWW + c * 25 + k];
  __syncthreads();
  float s = 0.f, sq = 0.f;
  for (int i = threadIdx.x; i < 16384; i += 256) {
    int y = i >> 7, xw = i & 127;
    float acc = 0.f;
#pragma unroll
    for (int ky = 0; ky < 5; ++ky)
#pragma unroll
      for (int kx = 0; kx < 5; ++kx)
        acc += w[ky * 5 + kx] * b2f(t[(y + ky) * 132 + xw + kx]);
    h1[(size_t)bc * 16384 + i] = acc;
    s += acc; sq += acc * acc;
  }
  for (int o = 32; o; o >>= 1) { s += __shfl_down(s, o, 64); sq += __shfl_down(sq, o, 64); }
  int wv = threadIdx.x >> 6;
  if ((threadIdx.x & 63) == 0) { red[wv] = s; red[4 + wv] = sq; }
  __syncthreads();
  if (threadIdx.x == 0) {
    float ts = red[0] + red[1] + red[2] + red[3];
    float tq = red[4] + red[5] + red[6] + red[7];
    int g = (b << 3) + (c >> 4);
    atomicAdd(&gst[g * 2], ts);
    atomicAdd(&gst[g * 2 + 1], tq);
  }
}

__global__ void k_stats(const float* __restrict__ gst, float* __restrict__ mr) {
  int g = threadIdx.x;
  if (g < 64) {
    const float invN = 1.f / 262144.f;
    float mean = gst[g * 2] * invN;
    float var = gst[g * 2 + 1] * invN - mean * mean;
    mr[g * 2] = mean;
    mr[g * 2 + 1] = rsqrtf(var + 1e-5f);
  }
}

// ---------------- K3: GN + exact GELU + 1x1 conv + tanh*8 -> offset (f32 out) ----
__global__ __launch_bounds__(128) void k_gn_off(const float* __restrict__ h1,
                                                const float* __restrict__ mr,
                                                const float* __restrict__ P,
                                                float* __restrict__ offf,
                                                float* __restrict__ dout) {
  int bh = blockIdx.x;
  int b = bh >> 7, h = bh & 127;
  int w = threadIdx.x;
  float acc = 0.f;
  for (int c = 0; c < 128; ++c) {
    float v = h1[(((size_t)(b * 128 + c)) * 128 + h) * 128 + w];
    int g = b * 8 + (c >> 4);
    float nv = (v - mr[g * 2]) * mr[g * 2 + 1] * P[P_GNG + c] + P[P_GNB + c];
    float ge = 0.5f * nv * (1.f + erff(nv * 0.70710678118f));
    acc += ge * P[P_PWW + c];
  }
  float off = acc + P[P_PWB];
  float ofv = tanhf(off) * 8.0f;
  offf[bh * 128 + w] = ofv;
  dout[16777216 + bh * 128 + w] = ofv;
}

// ---------------- K4: y-only grid sample + transpose -> seq f32 (l,c) ------------
__global__ __launch_bounds__(128) void k_deform(const void* __restrict__ x,
                                                const void* __restrict__ gng,
                                                const float* __restrict__ offf,
                                                float* __restrict__ seqc,
                                                int s0) {
  int bh = s0 + blockIdx.x;
  int b = bh >> 7, h = bh & 127;
  int w = threadIdx.x;
  bool f32x = in_is_f32(gng);
  __shared__ float t[128 * 130];
  float ofv = offf[bh * 128 + w];
  float gy = -1.f + (2.f / 127.f) * (float)h + ofv * (2.f / 127.f);
  gy = fminf(fmaxf(gy, -1.f), 1.f);
  float py = (gy + 1.f) * 0.5f * 127.f;
  py = fminf(fmaxf(py, 0.f), 127.f);
  float y0f = floorf(py);
  float wy = py - y0f;
  int y0 = (int)y0f;
  int y1 = min(y0 + 1, 127);
  const float* xfb = (const float*)x + (size_t)b * 128 * 16384;
  const unsigned short* xbb = (const unsigned short*)x + (size_t)b * 128 * 16384;
  for (int c = 0; c < 128; ++c) {
    size_t o0 = (size_t)c * 16384 + y0 * 128 + w;
    size_t o1 = (size_t)c * 16384 + y1 * 128 + w;
    float v0, v1;
    if (f32x) { v0 = xfb[o0]; v1 = xfb[o1]; }
    else      { v0 = b2f(xbb[o0]); v1 = b2f(xbb[o1]); }
    t[c * 130 + w] = v0 + wy * (v1 - v0);
  }
  __syncthreads();
  int c = threadIdx.x;
  float* sp = seqc + (size_t)blockIdx.x * 16384;
  for (int l = 0; l < 128; ++l) sp[l * 128 + c] = t[c * 130 + l];
}

// ---------------- G1: zxbcdt = seq @ wproj^T — LDS-tiled VALU --------------------
__global__ __launch_bounds__(256) void k_gemm1(const float* __restrict__ seqp,
                                               const float* __restrict__ wproj,
                                               const float* __restrict__ P,
                                               float* __restrict__ z,
                                               float* __restrict__ xbc,
                                               float* __restrict__ dtb) {
  __shared__ float As[16 * 129];
  __shared__ float Bs[16 * 129];
  int m0 = blockIdx.x * 16;
  int e0 = blockIdx.y * 16;
  for (int i = threadIdx.x; i < 2048; i += 256) {
    int row = i >> 7, k = i & 127;
    As[row * 129 + k] = seqp[(size_t)(m0 + row) * 128 + k];
    int e = e0 + row;
    Bs[row * 129 + k] = (e < 648) ? wproj[(size_t)e * 128 + k] : 0.f;
  }
  __syncthreads();
  int tx = threadIdx.x & 15;
  int ty = threadIdx.x >> 4;
  float acc = 0.f;
#pragma unroll 8
  for (int k = 0; k < 128; ++k) acc += As[ty * 129 + k] * Bs[tx * 129 + k];
  int m = m0 + ty;
  int e = e0 + tx;
  if (e < 256) {
    z[(size_t)m * 256 + e] = acc;
  } else if (e < 640) {
    xbc[(size_t)m * 384 + (e - 256)] = acc;
  } else if (e < 648) {
    float dv = acc + P[P_DTB + e - 640];
    float sp = (dv > 20.f) ? dv : log1pf(__expf(dv));
    dtb[(size_t)m * 8 + (e - 640)] = sp;
  }
}

// ---------------- K5: causal conv1d + SiLU, out-of-place -------------------------
__global__ __launch_bounds__(256) void k_conv1d_v2(const float* __restrict__ xbc,
                                                   float* __restrict__ pc,
                                                   const float* __restrict__ P) {
  const float* in = xbc + (size_t)blockIdx.x * 49152;   // 128*384
  float* out = pc + (size_t)blockIdx.x * 49152;
  for (int e = threadIdx.x; e < 384; e += 256) {
    float w0 = P[P_CW + e * 4 + 0], w1 = P[P_CW + e * 4 + 1];
    float w2 = P[P_CW + e * 4 + 2], w3 = P[P_CW + e * 4 + 3];
    float bb = P[P_CB + e];
    float x0 = 0.f, x1 = 0.f, x2 = 0.f;
    for (int l = 0; l < 128; ++l) {
      float x3 = in[l * 384 + e];
      float a = bb + w0 * x0 + w1 * x1 + w2 * x2 + w3 * x3;
      out[l * 384 + e] = a / (1.f + __expf(-a));
      x0 = x1; x1 = x2; x2 = x3;
    }
  }
}

// ---------------- K6: selective scan v3. block=seq; thread=(head,d) --------------
// h[64] FULLY unrolled -> stays in VGPRs (partial unroll left runtime-indexed
// accesses -> scratch spill: VGPR=20, ~870MB scratch writes/dispatch, 600us).
// B/C staged in LDS 16 l-steps at a time: barriers 256 -> 16 per block.
__global__ __launch_bounds__(256) void k_scan_v3(const float* __restrict__ pc,
                                                 const float* __restrict__ dtb,
                                                 const float* __restrict__ P,
                                                 float* __restrict__ ys) {
  int seq = blockIdx.x;
  int head = threadIdx.x >> 5;    // 0..7
  int d = threadIdx.x & 31;       // 0..31
  float A = -__expf(P[P_ALOG + head]);
  float Dk = P[P_DSKIP + head];
  float h[64];
#pragma unroll
  for (int s = 0; s < 64; ++s) h[s] = 0.f;
  __shared__ float sBC[16][128];  // [l-substep][B 0..63 | C 64..127], 8 KB
  const float* base = pc + (size_t)seq * 49152;
  const float* dtp = dtb + (size_t)seq * 1024;
  float* yp = ys + (size_t)seq * 32768;
  for (int lt = 0; lt < 128; lt += 16) {
    // Stage B,C for 16 steps: 2048 floats, 8 per thread, coalesced rows.
    for (int i = threadIdx.x; i < 2048; i += 256) {
      int ll = i >> 7, s = i & 127;
      sBC[ll][s] = base[(size_t)(lt + ll) * 384 + 256 + s];
    }
    __syncthreads();
#pragma unroll 1
    for (int ll = 0; ll < 16; ++ll) {
      int l = lt + ll;
      float dt = dtp[l * 8 + head];
      float dA = __expf(dt * A);
      float xv = base[l * 384 + head * 32 + d];
      float coef = dt * xv;
      float acc = 0.f;
#pragma unroll
      for (int s = 0; s < 64; ++s) {
        h[s] = h[s] * dA + coef * sBC[ll][s];
        acc += h[s] * sBC[ll][64 + s];
      }
      yp[l * 256 + head * 32 + d] = acc + Dk * xv;
    }
    __syncthreads();
  }
}

// ---------------- K7: gate + RMS norm, block per token ---------------------------
__global__ __launch_bounds__(256) void k_gate_v2(const float* __restrict__ ys,
                                                 const float* __restrict__ z,
                                                 const float* __restrict__ P,
                                                 float* __restrict__ ynorm) {
  int l = blockIdx.x;
  int e = threadIdx.x;
  __shared__ float red[4];
  float yv = ys[(size_t)l * 256 + e];
  float zv = z[(size_t)l * 256 + e];
  float g = zv / (1.f + __expf(-zv));
  float y = yv * g;
  float ss = y * y;
  for (int o = 32; o; o >>= 1) ss += __shfl_down(ss, o, 64);
  if ((threadIdx.x & 63) == 0) red[threadIdx.x >> 6] = ss;
  __syncthreads();
  float tot = red[0] + red[1] + red[2] + red[3];
  float r = rsqrtf(tot * (1.f / 256.f) + 1e-5f);
  ynorm[(size_t)l * 256 + e] = y * r * P[P_NG + e];
}

// ---------------- G2: out GEMM — LDS-tiled VALU, f32 NCHW store ------------------
__global__ __launch_bounds__(256) void k_gemm2(const float* __restrict__ ynorm,
                                               const float* __restrict__ outw,
                                               float* __restrict__ dout,
                                               int tok0) {
  __shared__ float As[16 * 257];
  __shared__ float Bs[16 * 257];
  int c0 = blockIdx.x * 16;
  int t0 = blockIdx.y * 16;
  for (int i = threadIdx.x; i < 4096; i += 256) {
    int row = i >> 8, k = i & 255;
    As[row * 257 + k] = outw[(size_t)(c0 + row) * 256 + k];
    Bs[row * 257 + k] = ynorm[(size_t)(t0 + row) * 256 + k];
  }
  __syncthreads();
  int tx = threadIdx.x & 15;
  int ty = threadIdx.x >> 4;
  float acc = 0.f;
#pragma unroll 8
  for (int k = 0; k < 256; ++k) acc += As[ty * 257 + k] * Bs[tx * 257 + k];
  int cc = c0 + ty;
  int l = tok0 + t0 + tx;
  int b = l >> 14, rem = l & 16383;
  int hh = rem >> 7, ww = rem & 127;
  dout[(((size_t)(b * 128 + cc) * 128 + hh) * 128 + ww)] = acc;
}

extern "C" void kernel_launch(void* const* d_in, const int* in_sizes, int n_in,
                              void* d_out, int out_size, void* d_ws, size_t ws_size,
                              hipStream_t stream) {
  const void* x      = d_in[0];
  const void* dww    = d_in[1];
  const void* gng    = d_in[2];
  const void* gnb    = d_in[3];
  const void* pww    = d_in[4];
  const void* pwb    = d_in[5];
  const void* wproj  = d_in[6];
  const void* cw     = d_in[7];
  const void* cb     = d_in[8];
  const void* dtbias = d_in[9];
  const void* alog   = d_in[10];
  const void* dskip  = d_in[11];
  const void* ng     = d_in[12];
  const void* outw   = d_in[13];
  float* out = (float*)d_out;

  // ws layout (bytes):
  //   0        gst (512)
  //   4096     mr (512)
  //   8192     P (32768)        -> 40960
  //   40960    wprojf (331776)  -> 372736
  //   372736   outwf (131072)   -> 503808
  //   503808   offf (524288)    -> 1028096
  //   1028096  chunk buffers
  char* ws = (char*)d_ws;
  float* gst    = (float*)(ws + 0);
  float* mr     = (float*)(ws + 4096);
  float* P      = (float*)(ws + 8192);
  float* wprojf = (float*)(ws + 40960);
  float* outwf  = (float*)(ws + 372736);
  float* offf   = (float*)(ws + 503808);
  char* cbase   = ws + 1028096;

  // h1 (f32, 67,108,864 B) lives in d_out's out_2d region.
  float* h1f = out;

  // Per-sequence chunk bytes: seq 65536 + z 131072 + xbc 196608 + pc 196608
  //                         + dtb 4096 + ys 131072 + ynorm 131072 = 856064.
  const int opts[11] = {1024, 512, 256, 128, 64, 32, 16, 8, 4, 2, 1};
  int CH = 1;
  for (int i = 0; i < 11; ++i) {
    if (1028096ull + (unsigned long long)opts[i] * 856064ull <= (unsigned long long)ws_size) {
      CH = opts[i];
      break;
    }
  }
  int NC = 1024 / CH;

  float* seqf = (float*)(cbase);
  float* zf   = (float*)(cbase + (size_t)CH * 65536);
  float* xbcf = (float*)(cbase + (size_t)CH * 196608);
  float* pcf  = (float*)(cbase + (size_t)CH * 393216);
  float* dtbf = (float*)(cbase + (size_t)CH * 589824);
  float* ysf  = (float*)(cbase + (size_t)CH * 593920);
  float* ynf  = (float*)(cbase + (size_t)CH * 724992);

  k_prep_params<<<1, 256, 0, stream>>>(dww, cw, cb, gng, gnb, pww, pwb, dtbias,
                                       alog, dskip, ng, P, gst);
  k_prep_w<<<128, 256, 0, stream>>>(wproj, outw, gng, wprojf, outwf);
  k_dwconv<<<1024, 256, 0, stream>>>(x, gng, P, h1f, gst);
  k_stats<<<1, 64, 0, stream>>>(gst, mr);
  k_gn_off<<<1024, 128, 0, stream>>>(h1f, mr, P, offf, out);

  for (int c = 0; c < NC; ++c) {
    int s0 = c * CH;
    k_deform<<<CH, 128, 0, stream>>>(x, gng, offf, seqf, s0);
    k_gemm1<<<dim3(CH * 8, 41), 256, 0, stream>>>(seqf, wprojf, P, zf, xbcf, dtbf);
    k_conv1d_v2<<<CH, 256, 0, stream>>>(xbcf, pcf, P);
    k_scan_v3<<<CH, 256, 0, stream>>>(pcf, dtbf, P, ysf);
    k_gate_v2<<<CH * 128, 256, 0, stream>>>(ysf, zf, P, ynf);
    k_gemm2<<<dim3(8, CH * 8), 256, 0, stream>>>(ynf, outwf, out, s0 * 128);
  }
}

// Round 2
// 2005.194 us; speedup vs baseline: 2.4538x; 1.6549x over previous
//
#include <hip/hip_runtime.h>
#include <math.h>

// B=8, C=128, H=128, W=128, D_INNER=256, D_STATE=64, HEADDIM=32, NHEADS=8,
// D_CONV=4, GN_GROUPS=8, D_XBC=384, D_INPROJ=648.
// Inputs f32 (probed via gn_g word0). OUTPUT IS F32 (reference output dtype).
// d_out = [out_2d: 16,777,216 f32][offset: 131,072 f32].
// h1 (f32) is staged in d_out's out_2d region (written by dwconv, read by gn_off,
// later fully overwritten by gemm2).

__device__ __forceinline__ float b2f(unsigned short u) {
  return __uint_as_float(((unsigned int)u) << 16);
}
__device__ __forceinline__ unsigned short f2b(float f) {
  unsigned int u = __float_as_uint(f);
  unsigned int r = (u + 0x7FFFu + ((u >> 16) & 1u)) >> 16;  // RNE
  return (unsigned short)r;
}
__device__ __forceinline__ bool in_is_f32(const void* gng) {
  return ((const unsigned int*)gng)[0] == 0x3F800000u;
}

#define P_DWW 0
#define P_CW 3200
#define P_CB 4736
#define P_GNG 5120
#define P_GNB 5248
#define P_PWW 5376
#define P_PWB 5504
#define P_DTB 5505
#define P_ALOG 5513
#define P_DSKIP 5521
#define P_NG 5529

__global__ void k_prep_params(const void* dww, const void* cw, const void* cb,
                              const void* gng, const void* gnb, const void* pww,
                              const void* pwb, const void* dtbias, const void* alog,
                              const void* dskip, const void* ng, float* __restrict__ P,
                              float* __restrict__ gst) {
  bool f = in_is_f32(gng);
  int tid = threadIdx.x;
  if (tid < 128) gst[tid] = 0.f;
  auto cvt = [&](const void* src, int n, int off) {
    for (int i = tid; i < n; i += 256)
      P[off + i] = f ? ((const float*)src)[i] : b2f(((const unsigned short*)src)[i]);
  };
  cvt(dww, 3200, P_DWW);
  cvt(cw, 1536, P_CW);
  cvt(cb, 384, P_CB);
  cvt(gng, 128, P_GNG);
  cvt(gnb, 128, P_GNB);
  cvt(pww, 128, P_PWW);
  cvt(pwb, 1, P_PWB);
  cvt(dtbias, 8, P_DTB);
  cvt(alog, 8, P_ALOG);
  cvt(dskip, 8, P_DSKIP);
  cvt(ng, 256, P_NG);
}

__global__ void k_prep_w(const void* wproj, const void* outw, const void* gng,
                         float* __restrict__ wprojf, float* __restrict__ outwf) {
  bool f = in_is_f32(gng);
  int stride = gridDim.x * blockDim.x;
  for (int i = blockIdx.x * blockDim.x + threadIdx.x; i < 82944; i += stride)
    wprojf[i] = f ? ((const float*)wproj)[i] : b2f(((const unsigned short*)wproj)[i]);
  for (int i = blockIdx.x * blockDim.x + threadIdx.x; i < 32768; i += stride)
    outwf[i] = f ? ((const float*)outw)[i] : b2f(((const unsigned short*)outw)[i]);
}

// ---------------- K1: depthwise 5x5 conv (SAME, zero pad) + group stats ----------
// x staged in LDS as bf16 (f32 tile would exceed 64KB static LDS); h1 out f32.
__global__ __launch_bounds__(256) void k_dwconv(const void* __restrict__ x,
                                                const void* __restrict__ gng,
                                                const float* __restrict__ P,
                                                float* __restrict__ h1,
                                                float* __restrict__ gst) {
  int bc = blockIdx.x;
  int b = bc >> 7, c = bc & 127;
  bool f32x = in_is_f32(gng);
  __shared__ unsigned short t[132 * 132];
  __shared__ float red[8];
  for (int i = threadIdx.x; i < 132 * 132; i += 256) t[i] = 0;
  __syncthreads();
  const float* xf = (const float*)x + (size_t)bc * 16384;
  const unsigned short* xb = (const unsigned short*)x + (size_t)bc * 16384;
  for (int i = threadIdx.x; i < 16384; i += 256) {
    int y = i >> 7, xw = i & 127;
    t[(y + 2) * 132 + xw + 2] = f32x ? f2b(xf[i]) : xb[i];
  }
  float w[25];
#pragma unroll
  for (int k = 0; k < 25; ++k) w[k] = P[P_DWW + c * 25 + k];
  __syncthreads();
  float s = 0.f, sq = 0.f;
  for (int i = threadIdx.x; i < 16384; i += 256) {
    int y = i >> 7, xw = i & 127;
    float acc = 0.f;
#pragma unroll
    for (int ky = 0; ky < 5; ++ky)
#pragma unroll
      for (int kx = 0; kx < 5; ++kx)
        acc += w[ky * 5 + kx] * b2f(t[(y + ky) * 132 + xw + kx]);
    h1[(size_t)bc * 16384 + i] = acc;
    s += acc; sq += acc * acc;
  }
  for (int o = 32; o; o >>= 1) { s += __shfl_down(s, o, 64); sq += __shfl_down(sq, o, 64); }
  int wv = threadIdx.x >> 6;
  if ((threadIdx.x & 63) == 0) { red[wv] = s; red[4 + wv] = sq; }
  __syncthreads();
  if (threadIdx.x == 0) {
    float ts = red[0] + red[1] + red[2] + red[3];
    float tq = red[4] + red[5] + red[6] + red[7];
    int g = (b << 3) + (c >> 4);
    atomicAdd(&gst[g * 2], ts);
    atomicAdd(&gst[g * 2 + 1], tq);
  }
}

__global__ void k_stats(const float* __restrict__ gst, float* __restrict__ mr) {
  int g = threadIdx.x;
  if (g < 64) {
    const float invN = 1.f / 262144.f;
    float mean = gst[g * 2] * invN;
    float var = gst[g * 2 + 1] * invN - mean * mean;
    mr[g * 2] = mean;
    mr[g * 2 + 1] = rsqrtf(var + 1e-5f);
  }
}

// ---------------- K3: GN + exact GELU + 1x1 conv + tanh*8 -> offset (f32 out) ----
__global__ __launch_bounds__(128) void k_gn_off(const float* __restrict__ h1,
                                                const float* __restrict__ mr,
                                                const float* __restrict__ P,
                                                float* __restrict__ offf,
                                                float* __restrict__ dout) {
  int bh = blockIdx.x;
  int b = bh >> 7, h = bh & 127;
  int w = threadIdx.x;
  float acc = 0.f;
  for (int c = 0; c < 128; ++c) {
    float v = h1[(((size_t)(b * 128 + c)) * 128 + h) * 128 + w];
    int g = b * 8 + (c >> 4);
    float nv = (v - mr[g * 2]) * mr[g * 2 + 1] * P[P_GNG + c] + P[P_GNB + c];
    float ge = 0.5f * nv * (1.f + erff(nv * 0.70710678118f));
    acc += ge * P[P_PWW + c];
  }
  float off = acc + P[P_PWB];
  float ofv = tanhf(off) * 8.0f;
  offf[bh * 128 + w] = ofv;
  dout[16777216 + bh * 128 + w] = ofv;
}

// ---------------- K4: y-only grid sample + transpose -> seq f32 (l,c) ------------
__global__ __launch_bounds__(128) void k_deform(const void* __restrict__ x,
                                                const void* __restrict__ gng,
                                                const float* __restrict__ offf,
                                                float* __restrict__ seqc,
                                                int s0) {
  int bh = s0 + blockIdx.x;
  int b = bh >> 7, h = bh & 127;
  int w = threadIdx.x;
  bool f32x = in_is_f32(gng);
  __shared__ float t[128 * 130];
  float ofv = offf[bh * 128 + w];
  float gy = -1.f + (2.f / 127.f) * (float)h + ofv * (2.f / 127.f);
  gy = fminf(fmaxf(gy, -1.f), 1.f);
  float py = (gy + 1.f) * 0.5f * 127.f;
  py = fminf(fmaxf(py, 0.f), 127.f);
  float y0f = floorf(py);
  float wy = py - y0f;
  int y0 = (int)y0f;
  int y1 = min(y0 + 1, 127);
  const float* xfb = (const float*)x + (size_t)b * 128 * 16384;
  const unsigned short* xbb = (const unsigned short*)x + (size_t)b * 128 * 16384;
  for (int c = 0; c < 128; ++c) {
    size_t o0 = (size_t)c * 16384 + y0 * 128 + w;
    size_t o1 = (size_t)c * 16384 + y1 * 128 + w;
    float v0, v1;
    if (f32x) { v0 = xfb[o0]; v1 = xfb[o1]; }
    else      { v0 = b2f(xbb[o0]); v1 = b2f(xbb[o1]); }
    t[c * 130 + w] = v0 + wy * (v1 - v0);
  }
  __syncthreads();
  int c = threadIdx.x;
  float* sp = seqc + (size_t)blockIdx.x * 16384;
  for (int l = 0; l < 128; ++l) sp[l * 128 + c] = t[c * 130 + l];
}

// ---------------- G1 v3: zxbcdt = seq @ wproj^T — 64x64 tile, 4x4/thread ---------
// Old: 1 out/thread, 2x ds_read_b32 per FMA -> LDS-issue-bound (VALUBusy 47%,
// 14 TF). New: K-major LDS tiles (pad 68 words, 16B-aligned fragments), per
// k-step 2x ds_read_b128 feeds 16 FMAs -> VALU-bound.
__global__ __launch_bounds__(256) void k_gemm1_v3(const float* __restrict__ seqp,
                                                  const float* __restrict__ wproj,
                                                  const float* __restrict__ P,
                                                  float* __restrict__ z,
                                                  float* __restrict__ xbc,
                                                  float* __restrict__ dtb) {
  __shared__ float As[32 * 68];  // [k][m], m-pad 64->68
  __shared__ float Bs[32 * 68];  // [k][e]
  int m0 = blockIdx.x * 64;
  int e0 = blockIdx.y * 64;      // 0..640; y=10 has tail (648)
  int tx = threadIdx.x & 15;     // e quad
  int ty = threadIdx.x >> 4;     // m quad
  float acc[4][4] = {};
  for (int kt = 0; kt < 128; kt += 32) {
    // A: 64 rows x 32 k, float4 global reads (coalesced), transposed store.
    for (int i = threadIdx.x; i < 512; i += 256) {
      int m = i >> 3, k4 = (i & 7) * 4;
      float4 v = *(const float4*)&seqp[(size_t)(m0 + m) * 128 + kt + k4];
      As[(k4 + 0) * 68 + m] = v.x;
      As[(k4 + 1) * 68 + m] = v.y;
      As[(k4 + 2) * 68 + m] = v.z;
      As[(k4 + 3) * 68 + m] = v.w;
    }
    for (int i = threadIdx.x; i < 512; i += 256) {
      int e = i >> 3, k4 = (i & 7) * 4;
      float4 v = make_float4(0.f, 0.f, 0.f, 0.f);
      if (e0 + e < 648)
        v = *(const float4*)&wproj[(size_t)(e0 + e) * 128 + kt + k4];
      Bs[(k4 + 0) * 68 + e] = v.x;
      Bs[(k4 + 1) * 68 + e] = v.y;
      Bs[(k4 + 2) * 68 + e] = v.z;
      Bs[(k4 + 3) * 68 + e] = v.w;
    }
    __syncthreads();
#pragma unroll 8
    for (int k = 0; k < 32; ++k) {
      float4 a = *(const float4*)&As[k * 68 + ty * 4];
      float4 b = *(const float4*)&Bs[k * 68 + tx * 4];
      float av[4] = {a.x, a.y, a.z, a.w};
      float bv[4] = {b.x, b.y, b.z, b.w};
#pragma unroll
      for (int i = 0; i < 4; ++i)
#pragma unroll
        for (int j = 0; j < 4; ++j) acc[i][j] += av[i] * bv[j];
    }
    __syncthreads();
  }
#pragma unroll
  for (int i = 0; i < 4; ++i) {
    int m = m0 + ty * 4 + i;
#pragma unroll
    for (int j = 0; j < 4; ++j) {
      int e = e0 + tx * 4 + j;
      float v = acc[i][j];
      if (e < 256) {
        z[(size_t)m * 256 + e] = v;
      } else if (e < 640) {
        xbc[(size_t)m * 384 + (e - 256)] = v;
      } else if (e < 648) {
        float dv = v + P[P_DTB + e - 640];
        float sp = (dv > 20.f) ? dv : log1pf(__expf(dv));
        dtb[(size_t)m * 8 + (e - 640)] = sp;
      }
    }
  }
}

// ---------------- K5: causal conv1d + SiLU, out-of-place -------------------------
__global__ __launch_bounds__(256) void k_conv1d_v2(const float* __restrict__ xbc,
                                                   float* __restrict__ pc,
                                                   const float* __restrict__ P) {
  const float* in = xbc + (size_t)blockIdx.x * 49152;   // 128*384
  float* out = pc + (size_t)blockIdx.x * 49152;
  for (int e = threadIdx.x; e < 384; e += 256) {
    float w0 = P[P_CW + e * 4 + 0], w1 = P[P_CW + e * 4 + 1];
    float w2 = P[P_CW + e * 4 + 2], w3 = P[P_CW + e * 4 + 3];
    float bb = P[P_CB + e];
    float x0 = 0.f, x1 = 0.f, x2 = 0.f;
    for (int l = 0; l < 128; ++l) {
      float x3 = in[l * 384 + e];
      float a = bb + w0 * x0 + w1 * x1 + w2 * x2 + w3 * x3;
      out[l * 384 + e] = a / (1.f + __expf(-a));
      x0 = x1; x1 = x2; x2 = x3;
    }
  }
}

// ---------------- K6: selective scan v3. block=seq; thread=(head,d) --------------
// h[64] FULLY unrolled -> stays in VGPRs. B/C staged in LDS 16 l-steps at a time.
__global__ __launch_bounds__(256) void k_scan_v3(const float* __restrict__ pc,
                                                 const float* __restrict__ dtb,
                                                 const float* __restrict__ P,
                                                 float* __restrict__ ys) {
  int seq = blockIdx.x;
  int head = threadIdx.x >> 5;    // 0..7
  int d = threadIdx.x & 31;       // 0..31
  float A = -__expf(P[P_ALOG + head]);
  float Dk = P[P_DSKIP + head];
  float h[64];
#pragma unroll
  for (int s = 0; s < 64; ++s) h[s] = 0.f;
  __shared__ float sBC[16][128];  // [l-substep][B 0..63 | C 64..127], 8 KB
  const float* base = pc + (size_t)seq * 49152;
  const float* dtp = dtb + (size_t)seq * 1024;
  float* yp = ys + (size_t)seq * 32768;
  for (int lt = 0; lt < 128; lt += 16) {
    for (int i = threadIdx.x; i < 2048; i += 256) {
      int ll = i >> 7, s = i & 127;
      sBC[ll][s] = base[(size_t)(lt + ll) * 384 + 256 + s];
    }
    __syncthreads();
#pragma unroll 1
    for (int ll = 0; ll < 16; ++ll) {
      int l = lt + ll;
      float dt = dtp[l * 8 + head];
      float dA = __expf(dt * A);
      float xv = base[l * 384 + head * 32 + d];
      float coef = dt * xv;
      float acc = 0.f;
#pragma unroll
      for (int s = 0; s < 64; ++s) {
        h[s] = h[s] * dA + coef * sBC[ll][s];
        acc += h[s] * sBC[ll][64 + s];
      }
      yp[l * 256 + head * 32 + d] = acc + Dk * xv;
    }
    __syncthreads();
  }
}

// ---------------- K7: gate + RMS norm, block per token ---------------------------
__global__ __launch_bounds__(256) void k_gate_v2(const float* __restrict__ ys,
                                                 const float* __restrict__ z,
                                                 const float* __restrict__ P,
                                                 float* __restrict__ ynorm) {
  int l = blockIdx.x;
  int e = threadIdx.x;
  __shared__ float red[4];
  float yv = ys[(size_t)l * 256 + e];
  float zv = z[(size_t)l * 256 + e];
  float g = zv / (1.f + __expf(-zv));
  float y = yv * g;
  float ss = y * y;
  for (int o = 32; o; o >>= 1) ss += __shfl_down(ss, o, 64);
  if ((threadIdx.x & 63) == 0) red[threadIdx.x >> 6] = ss;
  __syncthreads();
  float tot = red[0] + red[1] + red[2] + red[3];
  float r = rsqrtf(tot * (1.f / 256.f) + 1e-5f);
  ynorm[(size_t)l * 256 + e] = y * r * P[P_NG + e];
}

// ---------------- G2 v3: out GEMM — 64x64 tile, 4x4/thread, f32 NCHW store -------
// A = ynorm[token][k], B = outw[c][k], K=256.
__global__ __launch_bounds__(256) void k_gemm2_v3(const float* __restrict__ ynorm,
                                                  const float* __restrict__ outw,
                                                  float* __restrict__ dout,
                                                  int tok0) {
  __shared__ float As[32 * 68];  // [k][token]
  __shared__ float Bs[32 * 68];  // [k][c]
  int t0 = blockIdx.x * 64;
  int c0 = blockIdx.y * 64;      // 0 or 64
  int tx = threadIdx.x & 15;     // c quad
  int ty = threadIdx.x >> 4;     // token quad
  float acc[4][4] = {};
  for (int kt = 0; kt < 256; kt += 32) {
    for (int i = threadIdx.x; i < 512; i += 256) {
      int m = i >> 3, k4 = (i & 7) * 4;
      float4 v = *(const float4*)&ynorm[(size_t)(t0 + m) * 256 + kt + k4];
      As[(k4 + 0) * 68 + m] = v.x;
      As[(k4 + 1) * 68 + m] = v.y;
      As[(k4 + 2) * 68 + m] = v.z;
      As[(k4 + 3) * 68 + m] = v.w;
    }
    for (int i = threadIdx.x; i < 512; i += 256) {
      int e = i >> 3, k4 = (i & 7) * 4;
      float4 v = *(const float4*)&outw[(size_t)(c0 + e) * 256 + kt + k4];
      Bs[(k4 + 0) * 68 + e] = v.x;
      Bs[(k4 + 1) * 68 + e] = v.y;
      Bs[(k4 + 2) * 68 + e] = v.z;
      Bs[(k4 + 3) * 68 + e] = v.w;
    }
    __syncthreads();
#pragma unroll 8
    for (int k = 0; k < 32; ++k) {
      float4 a = *(const float4*)&As[k * 68 + ty * 4];
      float4 b = *(const float4*)&Bs[k * 68 + tx * 4];
      float av[4] = {a.x, a.y, a.z, a.w};
      float bv[4] = {b.x, b.y, b.z, b.w};
#pragma unroll
      for (int i = 0; i < 4; ++i)
#pragma unroll
        for (int j = 0; j < 4; ++j) acc[i][j] += av[i] * bv[j];
    }
    __syncthreads();
  }
#pragma unroll
  for (int i = 0; i < 4; ++i) {
    int l = tok0 + t0 + ty * 4 + i;
    int b = l >> 14, rem = l & 16383;
    int hh = rem >> 7, ww = rem & 127;
#pragma unroll
    for (int j = 0; j < 4; ++j) {
      int cc = c0 + tx * 4 + j;
      dout[(((size_t)(b * 128 + cc) * 128 + hh) * 128 + ww)] = acc[i][j];
    }
  }
}

extern "C" void kernel_launch(void* const* d_in, const int* in_sizes, int n_in,
                              void* d_out, int out_size, void* d_ws, size_t ws_size,
                              hipStream_t stream) {
  const void* x      = d_in[0];
  const void* dww    = d_in[1];
  const void* gng    = d_in[2];
  const void* gnb    = d_in[3];
  const void* pww    = d_in[4];
  const void* pwb    = d_in[5];
  const void* wproj  = d_in[6];
  const void* cw     = d_in[7];
  const void* cb     = d_in[8];
  const void* dtbias = d_in[9];
  const void* alog   = d_in[10];
  const void* dskip  = d_in[11];
  const void* ng     = d_in[12];
  const void* outw   = d_in[13];
  float* out = (float*)d_out;

  // ws layout (bytes):
  //   0        gst (512)
  //   4096     mr (512)
  //   8192     P (32768)        -> 40960
  //   40960    wprojf (331776)  -> 372736
  //   372736   outwf (131072)   -> 503808
  //   503808   offf (524288)    -> 1028096
  //   1028096  chunk buffers
  char* ws = (char*)d_ws;
  float* gst    = (float*)(ws + 0);
  float* mr     = (float*)(ws + 4096);
  float* P      = (float*)(ws + 8192);
  float* wprojf = (float*)(ws + 40960);
  float* outwf  = (float*)(ws + 372736);
  float* offf   = (float*)(ws + 503808);
  char* cbase   = ws + 1028096;

  // h1 (f32, 67,108,864 B) lives in d_out's out_2d region.
  float* h1f = out;

  // Per-sequence chunk bytes: seq 65536 + z 131072 + xbc 196608 + pc 196608
  //                         + dtb 4096 + ys 131072 + ynorm 131072 = 856064.
  const int opts[11] = {1024, 512, 256, 128, 64, 32, 16, 8, 4, 2, 1};
  int CH = 1;
  for (int i = 0; i < 11; ++i) {
    if (1028096ull + (unsigned long long)opts[i] * 856064ull <= (unsigned long long)ws_size) {
      CH = opts[i];
      break;
    }
  }
  int NC = 1024 / CH;

  float* seqf = (float*)(cbase);
  float* zf   = (float*)(cbase + (size_t)CH * 65536);
  float* xbcf = (float*)(cbase + (size_t)CH * 196608);
  float* pcf  = (float*)(cbase + (size_t)CH * 393216);
  float* dtbf = (float*)(cbase + (size_t)CH * 589824);
  float* ysf  = (float*)(cbase + (size_t)CH * 593920);
  float* ynf  = (float*)(cbase + (size_t)CH * 724992);

  k_prep_params<<<1, 256, 0, stream>>>(dww, cw, cb, gng, gnb, pww, pwb, dtbias,
                                       alog, dskip, ng, P, gst);
  k_prep_w<<<128, 256, 0, stream>>>(wproj, outw, gng, wprojf, outwf);
  k_dwconv<<<1024, 256, 0, stream>>>(x, gng, P, h1f, gst);
  k_stats<<<1, 64, 0, stream>>>(gst, mr);
  k_gn_off<<<1024, 128, 0, stream>>>(h1f, mr, P, offf, out);

  for (int c = 0; c < NC; ++c) {
    int s0 = c * CH;
    k_deform<<<CH, 128, 0, stream>>>(x, gng, offf, seqf, s0);
    k_gemm1_v3<<<dim3(CH * 2, 11), 256, 0, stream>>>(seqf, wprojf, P, zf, xbcf, dtbf);
    k_conv1d_v2<<<CH, 256, 0, stream>>>(xbcf, pcf, P);
    k_scan_v3<<<CH, 256, 0, stream>>>(pcf, dtbf, P, ysf);
    k_gate_v2<<<CH * 128, 256, 0, stream>>>(ysf, zf, P, ynf);
    k_gemm2_v3<<<dim3(CH * 2, 2), 256, 0, stream>>>(ynf, outwf, out, s0 * 128);
  }
}

// Round 4
// 1872.585 us; speedup vs baseline: 2.6276x; 1.0708x over previous
//
#include <hip/hip_runtime.h>
#include <math.h>

// B=8, C=128, H=128, W=128, D_INNER=256, D_STATE=64, HEADDIM=32, NHEADS=8,
// D_CONV=4, GN_GROUPS=8, D_XBC=384, D_INPROJ=648.
// Inputs f32 (probed via gn_g word0). OUTPUT IS F32 (reference output dtype).
// d_out = [out_2d: 16,777,216 f32][offset: 131,072 f32].
// h1 (f32) is staged in d_out's out_2d region (written by dwconv, read by gn_off,
// later fully overwritten by gemm2).

__device__ __forceinline__ float b2f(unsigned short u) {
  return __uint_as_float(((unsigned int)u) << 16);
}
__device__ __forceinline__ bool in_is_f32(const void* gng) {
  return ((const unsigned int*)gng)[0] == 0x3F800000u;
}

#define P_DWW 0
#define P_CW 3200
#define P_CB 4736
#define P_GNG 5120
#define P_GNB 5248
#define P_PWW 5376
#define P_PWB 5504
#define P_DTB 5505
#define P_ALOG 5513
#define P_DSKIP 5521
#define P_NG 5529

__global__ void k_prep_params(const void* dww, const void* cw, const void* cb,
                              const void* gng, const void* gnb, const void* pww,
                              const void* pwb, const void* dtbias, const void* alog,
                              const void* dskip, const void* ng, float* __restrict__ P,
                              float* __restrict__ gst) {
  bool f = in_is_f32(gng);
  int tid = threadIdx.x;
  if (tid < 128) gst[tid] = 0.f;
  auto cvt = [&](const void* src, int n, int off) {
    for (int i = tid; i < n; i += 256)
      P[off + i] = f ? ((const float*)src)[i] : b2f(((const unsigned short*)src)[i]);
  };
  cvt(dww, 3200, P_DWW);
  cvt(cw, 1536, P_CW);
  cvt(cb, 384, P_CB);
  cvt(gng, 128, P_GNG);
  cvt(gnb, 128, P_GNB);
  cvt(pww, 128, P_PWW);
  cvt(pwb, 1, P_PWB);
  cvt(dtbias, 8, P_DTB);
  cvt(alog, 8, P_ALOG);
  cvt(dskip, 8, P_DSKIP);
  cvt(ng, 256, P_NG);
}

__global__ void k_prep_w(const void* wproj, const void* outw, const void* gng,
                         float* __restrict__ wprojf, float* __restrict__ outwf) {
  bool f = in_is_f32(gng);
  int stride = gridDim.x * blockDim.x;
  for (int i = blockIdx.x * blockDim.x + threadIdx.x; i < 82944; i += stride)
    wprojf[i] = f ? ((const float*)wproj)[i] : b2f(((const unsigned short*)wproj)[i]);
  for (int i = blockIdx.x * blockDim.x + threadIdx.x; i < 32768; i += stride)
    outwf[i] = f ? ((const float*)outw)[i] : b2f(((const unsigned short*)outw)[i]);
}

// ---------------- K1 v2: depthwise 5x5 conv + group stats ------------------------
// f32 tile (132 rows x 136 cols), column-sliding walk with 5-slot output ring:
// 5 ds_read_b32 + 25 FMA per pixel. All ring indices compile-time.
// BUGFIX (round 3): the H0=64 half's first 4 rows contributed to dy=60..63
// (other half's outputs); those slots were reused for dy=65..68 without being
// cleared -> contamination. Prologue now masks ky<=u (dy>=H0). For H0=0 the
// masked-off contributions were zero (pad rows), so behavior there unchanged.
template <int H0>
__device__ __forceinline__ void dw_col(const float* __restrict__ t,
                                       const float* __restrict__ w, int col,
                                       float* __restrict__ h1, size_t outbase,
                                       float& s, float& sq) {
  float acc[5] = {0.f, 0.f, 0.f, 0.f, 0.f};
  // Prologue: r = H0+u, u=0..4 — only ky<=u valid (dy = r-ky >= H0).
#pragma unroll
  for (int u = 0; u < 5; ++u) {
    int r = H0 + u;
    const float* row = t + r * 136 + col + 2;
    float v0 = row[0], v1 = row[1], v2 = row[2], v3 = row[3], v4 = row[4];
#pragma unroll
    for (int ky = 0; ky <= u; ++ky) {
      int sl = (H0 + u + 5 - ky) % 5;
      acc[sl] += w[ky * 5 + 0] * v0 + w[ky * 5 + 1] * v1 + w[ky * 5 + 2] * v2 +
                 w[ky * 5 + 3] * v3 + w[ky * 5 + 4] * v4;
    }
    if (u == 4) {  // retire dy = H0
      int sl = H0 % 5;
      float ov = acc[sl];
      h1[outbase + (size_t)H0 * 128 + col] = ov;
      s += ov; sq += ov * ov;
      acc[sl] = 0.f;
    }
  }
  // Main: r = H0 + 5*o + u, o=1..12 — all ky valid, retire dy=r-4 each step.
  for (int o = 1; o < 13; ++o) {
#pragma unroll
    for (int u = 0; u < 5; ++u) {
      int r = H0 + o * 5 + u;
      const float* row = t + r * 136 + col + 2;
      float v0 = row[0], v1 = row[1], v2 = row[2], v3 = row[3], v4 = row[4];
#pragma unroll
      for (int ky = 0; ky < 5; ++ky) {
        int sl = (H0 + u + 5 - ky) % 5;  // dy = r - ky (compile-time slot)
        acc[sl] += w[ky * 5 + 0] * v0 + w[ky * 5 + 1] * v1 + w[ky * 5 + 2] * v2 +
                   w[ky * 5 + 3] * v3 + w[ky * 5 + 4] * v4;
      }
      int dy = r - 4;
      int sl = (H0 + u + 1) % 5;
      float ov = acc[sl];
      h1[outbase + (size_t)dy * 128 + col] = ov;
      s += ov; sq += ov * ov;
      acc[sl] = 0.f;
    }
  }
  // Epilogue: r = H0+65..H0+67, retire dy = H0+61..H0+63. Rows beyond data are
  // zero-pad; extra contributions land in never-retired slots.
#pragma unroll
  for (int u = 0; u < 3; ++u) {
    int r = H0 + 65 + u;
    const float* row = t + r * 136 + col + 2;
    float v0 = row[0], v1 = row[1], v2 = row[2], v3 = row[3], v4 = row[4];
#pragma unroll
    for (int ky = 0; ky < 5; ++ky) {
      int sl = (H0 + u + 5 - ky) % 5;
      acc[sl] += w[ky * 5 + 0] * v0 + w[ky * 5 + 1] * v1 + w[ky * 5 + 2] * v2 +
                 w[ky * 5 + 3] * v3 + w[ky * 5 + 4] * v4;
    }
    int dy = r - 4;
    int sl = (H0 + u + 1) % 5;
    float ov = acc[sl];
    h1[outbase + (size_t)dy * 128 + col] = ov;
    s += ov; sq += ov * ov;
    acc[sl] = 0.f;
  }
}

__global__ __launch_bounds__(256) void k_dwconv_v2(const void* __restrict__ x,
                                                   const void* __restrict__ gng,
                                                   const float* __restrict__ P,
                                                   float* __restrict__ h1,
                                                   float* __restrict__ gst) {
  int bc = blockIdx.x;
  int b = bc >> 7, chan = bc & 127;
  bool f32x = in_is_f32(gng);
  // Tile: row t_r = data_y + 2 (rows 0..131), col t_c = data_x + 4 (cols 4..131).
  __shared__ __align__(16) float t[132 * 136];  // 71,808 B
  __shared__ float red[8];
  for (int i = threadIdx.x; i < (132 * 136) / 4; i += 256)
    ((float4*)t)[i] = make_float4(0.f, 0.f, 0.f, 0.f);
  __syncthreads();
  const float* xf = (const float*)x + (size_t)bc * 16384;
  const unsigned short* xb = (const unsigned short*)x + (size_t)bc * 16384;
  for (int i = threadIdx.x; i < 4096; i += 256) {
    int dy = i >> 5, dc = (i & 31) * 4;
    float4 v;
    if (f32x) {
      v = *(const float4*)&xf[i * 4];
    } else {
      ushort4 r4 = *(const ushort4*)&xb[i * 4];
      v = make_float4(b2f(r4.x), b2f(r4.y), b2f(r4.z), b2f(r4.w));
    }
    *(float4*)&t[(dy + 2) * 136 + dc + 4] = v;
  }
  float w[25];
#pragma unroll
  for (int k = 0; k < 25; ++k) w[k] = P[P_DWW + chan * 25 + k];
  __syncthreads();
  int col = threadIdx.x & 127;
  float s = 0.f, sq = 0.f;
  size_t outbase = (size_t)bc * 16384;
  if (threadIdx.x < 128) dw_col<0>(t, w, col, h1, outbase, s, sq);
  else                   dw_col<64>(t, w, col, h1, outbase, s, sq);
  for (int o = 32; o; o >>= 1) { s += __shfl_down(s, o, 64); sq += __shfl_down(sq, o, 64); }
  int wv = threadIdx.x >> 6;
  if ((threadIdx.x & 63) == 0) { red[wv] = s; red[4 + wv] = sq; }
  __syncthreads();
  if (threadIdx.x == 0) {
    float ts = red[0] + red[1] + red[2] + red[3];
    float tq = red[4] + red[5] + red[6] + red[7];
    int g = (b << 3) + (chan >> 4);
    atomicAdd(&gst[g * 2], ts);
    atomicAdd(&gst[g * 2 + 1], tq);
  }
}

__global__ void k_stats(const float* __restrict__ gst, float* __restrict__ mr) {
  int g = threadIdx.x;
  if (g < 64) {
    const float invN = 1.f / 262144.f;
    float mean = gst[g * 2] * invN;
    float var = gst[g * 2 + 1] * invN - mean * mean;
    mr[g * 2] = mean;
    mr[g * 2 + 1] = rsqrtf(var + 1e-5f);
  }
}

// ---------------- K3: GN + exact GELU + 1x1 conv + tanh*8 -> offset (f32 out) ----
__global__ __launch_bounds__(128) void k_gn_off(const float* __restrict__ h1,
                                                const float* __restrict__ mr,
                                                const float* __restrict__ P,
                                                float* __restrict__ offf,
                                                float* __restrict__ dout) {
  int bh = blockIdx.x;
  int b = bh >> 7, h = bh & 127;
  int w = threadIdx.x;
  float acc = 0.f;
  for (int c = 0; c < 128; ++c) {
    float v = h1[(((size_t)(b * 128 + c)) * 128 + h) * 128 + w];
    int g = b * 8 + (c >> 4);
    float nv = (v - mr[g * 2]) * mr[g * 2 + 1] * P[P_GNG + c] + P[P_GNB + c];
    float ge = 0.5f * nv * (1.f + erff(nv * 0.70710678118f));
    acc += ge * P[P_PWW + c];
  }
  float off = acc + P[P_PWB];
  float ofv = tanhf(off) * 8.0f;
  offf[bh * 128 + w] = ofv;
  dout[16777216 + bh * 128 + w] = ofv;
}

// ---------------- K4: y-only grid sample + transpose -> seq f32 (l,c) ------------
// LDS stride 129 (odd): transpose-read banks = (c + l) mod 32 -> conflict-free.
__global__ __launch_bounds__(128) void k_deform(const void* __restrict__ x,
                                                const void* __restrict__ gng,
                                                const float* __restrict__ offf,
                                                float* __restrict__ seqc,
                                                int s0) {
  int bh = s0 + blockIdx.x;
  int b = bh >> 7, h = bh & 127;
  int w = threadIdx.x;
  bool f32x = in_is_f32(gng);
  __shared__ float t[128 * 129];
  float ofv = offf[bh * 128 + w];
  float gy = -1.f + (2.f / 127.f) * (float)h + ofv * (2.f / 127.f);
  gy = fminf(fmaxf(gy, -1.f), 1.f);
  float py = (gy + 1.f) * 0.5f * 127.f;
  py = fminf(fmaxf(py, 0.f), 127.f);
  float y0f = floorf(py);
  float wy = py - y0f;
  int y0 = (int)y0f;
  int y1 = min(y0 + 1, 127);
  const float* xfb = (const float*)x + (size_t)b * 128 * 16384;
  const unsigned short* xbb = (const unsigned short*)x + (size_t)b * 128 * 16384;
  for (int c = 0; c < 128; ++c) {
    size_t o0 = (size_t)c * 16384 + y0 * 128 + w;
    size_t o1 = (size_t)c * 16384 + y1 * 128 + w;
    float v0, v1;
    if (f32x) { v0 = xfb[o0]; v1 = xfb[o1]; }
    else      { v0 = b2f(xbb[o0]); v1 = b2f(xbb[o1]); }
    t[c * 129 + w] = v0 + wy * (v1 - v0);
  }
  __syncthreads();
  int c = threadIdx.x;
  float* sp = seqc + (size_t)blockIdx.x * 16384;
  for (int l = 0; l < 128; ++l) sp[l * 128 + c] = t[c * 129 + l];
}

// ---------------- G1 v3: zxbcdt = seq @ wproj^T — 64x64 tile, 4x4/thread ---------
__global__ __launch_bounds__(256) void k_gemm1_v3(const float* __restrict__ seqp,
                                                  const float* __restrict__ wproj,
                                                  const float* __restrict__ P,
                                                  float* __restrict__ z,
                                                  float* __restrict__ xbc,
                                                  float* __restrict__ dtb) {
  __shared__ float As[32 * 68];  // [k][m], m-pad 64->68
  __shared__ float Bs[32 * 68];  // [k][e]
  int m0 = blockIdx.x * 64;
  int e0 = blockIdx.y * 64;      // 0..640; y=10 has tail (648)
  int tx = threadIdx.x & 15;     // e quad
  int ty = threadIdx.x >> 4;     // m quad
  float acc[4][4] = {};
  for (int kt = 0; kt < 128; kt += 32) {
    for (int i = threadIdx.x; i < 512; i += 256) {
      int m = i >> 3, k4 = (i & 7) * 4;
      float4 v = *(const float4*)&seqp[(size_t)(m0 + m) * 128 + kt + k4];
      As[(k4 + 0) * 68 + m] = v.x;
      As[(k4 + 1) * 68 + m] = v.y;
      As[(k4 + 2) * 68 + m] = v.z;
      As[(k4 + 3) * 68 + m] = v.w;
    }
    for (int i = threadIdx.x; i < 512; i += 256) {
      int e = i >> 3, k4 = (i & 7) * 4;
      float4 v = make_float4(0.f, 0.f, 0.f, 0.f);
      if (e0 + e < 648)
        v = *(const float4*)&wproj[(size_t)(e0 + e) * 128 + kt + k4];
      Bs[(k4 + 0) * 68 + e] = v.x;
      Bs[(k4 + 1) * 68 + e] = v.y;
      Bs[(k4 + 2) * 68 + e] = v.z;
      Bs[(k4 + 3) * 68 + e] = v.w;
    }
    __syncthreads();
#pragma unroll 8
    for (int k = 0; k < 32; ++k) {
      float4 a = *(const float4*)&As[k * 68 + ty * 4];
      float4 b = *(const float4*)&Bs[k * 68 + tx * 4];
      float av[4] = {a.x, a.y, a.z, a.w};
      float bv[4] = {b.x, b.y, b.z, b.w};
#pragma unroll
      for (int i = 0; i < 4; ++i)
#pragma unroll
        for (int j = 0; j < 4; ++j) acc[i][j] += av[i] * bv[j];
    }
    __syncthreads();
  }
#pragma unroll
  for (int i = 0; i < 4; ++i) {
    int m = m0 + ty * 4 + i;
#pragma unroll
    for (int j = 0; j < 4; ++j) {
      int e = e0 + tx * 4 + j;
      float v = acc[i][j];
      if (e < 256) {
        z[(size_t)m * 256 + e] = v;
      } else if (e < 640) {
        xbc[(size_t)m * 384 + (e - 256)] = v;
      } else if (e < 648) {
        float dv = v + P[P_DTB + e - 640];
        float sp = (dv > 20.f) ? dv : log1pf(__expf(dv));
        dtb[(size_t)m * 8 + (e - 640)] = sp;
      }
    }
  }
}

// ---------------- K5: causal conv1d + SiLU, out-of-place -------------------------
__global__ __launch_bounds__(256) void k_conv1d_v2(const float* __restrict__ xbc,
                                                   float* __restrict__ pc,
                                                   const float* __restrict__ P) {
  const float* in = xbc + (size_t)blockIdx.x * 49152;   // 128*384
  float* out = pc + (size_t)blockIdx.x * 49152;
  for (int e = threadIdx.x; e < 384; e += 256) {
    float w0 = P[P_CW + e * 4 + 0], w1 = P[P_CW + e * 4 + 1];
    float w2 = P[P_CW + e * 4 + 2], w3 = P[P_CW + e * 4 + 3];
    float bb = P[P_CB + e];
    float x0 = 0.f, x1 = 0.f, x2 = 0.f;
    for (int l = 0; l < 128; ++l) {
      float x3 = in[l * 384 + e];
      float a = bb + w0 * x0 + w1 * x1 + w2 * x2 + w3 * x3;
      out[l * 384 + e] = a / (1.f + __expf(-a));
      x0 = x1; x1 = x2; x2 = x3;
    }
  }
}

// ---------------- K6: selective scan v3. block=seq; thread=(head,d) --------------
__global__ __launch_bounds__(256) void k_scan_v3(const float* __restrict__ pc,
                                                 const float* __restrict__ dtb,
                                                 const float* __restrict__ P,
                                                 float* __restrict__ ys) {
  int seq = blockIdx.x;
  int head = threadIdx.x >> 5;    // 0..7
  int d = threadIdx.x & 31;       // 0..31
  float A = -__expf(P[P_ALOG + head]);
  float Dk = P[P_DSKIP + head];
  float h[64];
#pragma unroll
  for (int s = 0; s < 64; ++s) h[s] = 0.f;
  __shared__ float sBC[16][128];  // [l-substep][B 0..63 | C 64..127], 8 KB
  const float* base = pc + (size_t)seq * 49152;
  const float* dtp = dtb + (size_t)seq * 1024;
  float* yp = ys + (size_t)seq * 32768;
  for (int lt = 0; lt < 128; lt += 16) {
    for (int i = threadIdx.x; i < 2048; i += 256) {
      int ll = i >> 7, s = i & 127;
      sBC[ll][s] = base[(size_t)(lt + ll) * 384 + 256 + s];
    }
    __syncthreads();
#pragma unroll 1
    for (int ll = 0; ll < 16; ++ll) {
      int l = lt + ll;
      float dt = dtp[l * 8 + head];
      float dA = __expf(dt * A);
      float xv = base[l * 384 + head * 32 + d];
      float coef = dt * xv;
      float acc = 0.f;
#pragma unroll
      for (int s = 0; s < 64; ++s) {
        h[s] = h[s] * dA + coef * sBC[ll][s];
        acc += h[s] * sBC[ll][64 + s];
      }
      yp[l * 256 + head * 32 + d] = acc + Dk * xv;
    }
    __syncthreads();
  }
}

// ---------------- K7: gate + RMS norm, block per token ---------------------------
__global__ __launch_bounds__(256) void k_gate_v2(const float* __restrict__ ys,
                                                 const float* __restrict__ z,
                                                 const float* __restrict__ P,
                                                 float* __restrict__ ynorm) {
  int l = blockIdx.x;
  int e = threadIdx.x;
  __shared__ float red[4];
  float yv = ys[(size_t)l * 256 + e];
  float zv = z[(size_t)l * 256 + e];
  float g = zv / (1.f + __expf(-zv));
  float y = yv * g;
  float ss = y * y;
  for (int o = 32; o; o >>= 1) ss += __shfl_down(ss, o, 64);
  if ((threadIdx.x & 63) == 0) red[threadIdx.x >> 6] = ss;
  __syncthreads();
  float tot = red[0] + red[1] + red[2] + red[3];
  float r = rsqrtf(tot * (1.f / 256.f) + 1e-5f);
  ynorm[(size_t)l * 256 + e] = y * r * P[P_NG + e];
}

// ---------------- G2 v3: out GEMM — 64x64 tile, 4x4/thread, f32 NCHW store -------
__global__ __launch_bounds__(256) void k_gemm2_v3(const float* __restrict__ ynorm,
                                                  const float* __restrict__ outw,
                                                  float* __restrict__ dout,
                                                  int tok0) {
  __shared__ float As[32 * 68];  // [k][token]
  __shared__ float Bs[32 * 68];  // [k][c]
  int t0 = blockIdx.x * 64;
  int c0 = blockIdx.y * 64;      // 0 or 64
  int tx = threadIdx.x & 15;     // c quad
  int ty = threadIdx.x >> 4;     // token quad
  float acc[4][4] = {};
  for (int kt = 0; kt < 256; kt += 32) {
    for (int i = threadIdx.x; i < 512; i += 256) {
      int m = i >> 3, k4 = (i & 7) * 4;
      float4 v = *(const float4*)&ynorm[(size_t)(t0 + m) * 256 + kt + k4];
      As[(k4 + 0) * 68 + m] = v.x;
      As[(k4 + 1) * 68 + m] = v.y;
      As[(k4 + 2) * 68 + m] = v.z;
      As[(k4 + 3) * 68 + m] = v.w;
    }
    for (int i = threadIdx.x; i < 512; i += 256) {
      int e = i >> 3, k4 = (i & 7) * 4;
      float4 v = *(const float4*)&outw[(size_t)(c0 + e) * 256 + kt + k4];
      Bs[(k4 + 0) * 68 + e] = v.x;
      Bs[(k4 + 1) * 68 + e] = v.y;
      Bs[(k4 + 2) * 68 + e] = v.z;
      Bs[(k4 + 3) * 68 + e] = v.w;
    }
    __syncthreads();
#pragma unroll 8
    for (int k = 0; k < 32; ++k) {
      float4 a = *(const float4*)&As[k * 68 + ty * 4];
      float4 b = *(const float4*)&Bs[k * 68 + tx * 4];
      float av[4] = {a.x, a.y, a.z, a.w};
      float bv[4] = {b.x, b.y, b.z, b.w};
#pragma unroll
      for (int i = 0; i < 4; ++i)
#pragma unroll
        for (int j = 0; j < 4; ++j) acc[i][j] += av[i] * bv[j];
    }
    __syncthreads();
  }
#pragma unroll
  for (int i = 0; i < 4; ++i) {
    int l = tok0 + t0 + ty * 4 + i;
    int b = l >> 14, rem = l & 16383;
    int hh = rem >> 7, ww = rem & 127;
#pragma unroll
    for (int j = 0; j < 4; ++j) {
      int cc = c0 + tx * 4 + j;
      dout[(((size_t)(b * 128 + cc) * 128 + hh) * 128 + ww)] = acc[i][j];
    }
  }
}

extern "C" void kernel_launch(void* const* d_in, const int* in_sizes, int n_in,
                              void* d_out, int out_size, void* d_ws, size_t ws_size,
                              hipStream_t stream) {
  const void* x      = d_in[0];
  const void* dww    = d_in[1];
  const void* gng    = d_in[2];
  const void* gnb    = d_in[3];
  const void* pww    = d_in[4];
  const void* pwb    = d_in[5];
  const void* wproj  = d_in[6];
  const void* cw     = d_in[7];
  const void* cb     = d_in[8];
  const void* dtbias = d_in[9];
  const void* alog   = d_in[10];
  const void* dskip  = d_in[11];
  const void* ng     = d_in[12];
  const void* outw   = d_in[13];
  float* out = (float*)d_out;

  char* ws = (char*)d_ws;
  float* gst    = (float*)(ws + 0);
  float* mr     = (float*)(ws + 4096);
  float* P      = (float*)(ws + 8192);
  float* wprojf = (float*)(ws + 40960);
  float* outwf  = (float*)(ws + 372736);
  float* offf   = (float*)(ws + 503808);
  char* cbase   = ws + 1028096;

  // h1 (f32, 67,108,864 B) lives in d_out's out_2d region.
  float* h1f = out;

  // Per-sequence chunk bytes: seq 65536 + z 131072 + xbc 196608 + pc 196608
  //                         + dtb 4096 + ys 131072 + ynorm 131072 = 856064.
  const int opts[11] = {1024, 512, 256, 128, 64, 32, 16, 8, 4, 2, 1};
  int CH = 1;
  for (int i = 0; i < 11; ++i) {
    if (1028096ull + (unsigned long long)opts[i] * 856064ull <= (unsigned long long)ws_size) {
      CH = opts[i];
      break;
    }
  }
  int NC = 1024 / CH;

  float* seqf = (float*)(cbase);
  float* zf   = (float*)(cbase + (size_t)CH * 65536);
  float* xbcf = (float*)(cbase + (size_t)CH * 196608);
  float* pcf  = (float*)(cbase + (size_t)CH * 393216);
  float* dtbf = (float*)(cbase + (size_t)CH * 589824);
  float* ysf  = (float*)(cbase + (size_t)CH * 593920);
  float* ynf  = (float*)(cbase + (size_t)CH * 724992);

  k_prep_params<<<1, 256, 0, stream>>>(dww, cw, cb, gng, gnb, pww, pwb, dtbias,
                                       alog, dskip, ng, P, gst);
  k_prep_w<<<128, 256, 0, stream>>>(wproj, outw, gng, wprojf, outwf);
  k_dwconv_v2<<<1024, 256, 0, stream>>>(x, gng, P, h1f, gst);
  k_stats<<<1, 64, 0, stream>>>(gst, mr);
  k_gn_off<<<1024, 128, 0, stream>>>(h1f, mr, P, offf, out);

  for (int c = 0; c < NC; ++c) {
    int s0 = c * CH;
    k_deform<<<CH, 128, 0, stream>>>(x, gng, offf, seqf, s0);
    k_gemm1_v3<<<dim3(CH * 2, 11), 256, 0, stream>>>(seqf, wprojf, P, zf, xbcf, dtbf);
    k_conv1d_v2<<<CH, 256, 0, stream>>>(xbcf, pcf, P);
    k_scan_v3<<<CH, 256, 0, stream>>>(pcf, dtbf, P, ysf);
    k_gate_v2<<<CH * 128, 256, 0, stream>>>(ysf, zf, P, ynf);
    k_gemm2_v3<<<dim3(CH * 2, 2), 256, 0, stream>>>(ynf, outwf, out, s0 * 128);
  }
}

// Round 5
// 1604.971 us; speedup vs baseline: 3.0657x; 1.1667x over previous
//
#include <hip/hip_runtime.h>
#include <math.h>

// B=8, C=128, H=128, W=128, D_INNER=256, D_STATE=64, HEADDIM=32, NHEADS=8,
// D_CONV=4, GN_GROUPS=8, D_XBC=384, D_INPROJ=648.
// Inputs f32 (probed via gn_g word0). OUTPUT IS F32 (reference output dtype).
// d_out = [out_2d: 16,777,216 f32][offset: 131,072 f32].
// h1 (f32) is staged in d_out's out_2d region.

__device__ __forceinline__ float b2f(unsigned short u) {
  return __uint_as_float(((unsigned int)u) << 16);
}
__device__ __forceinline__ bool in_is_f32(const void* gng) {
  return ((const unsigned int*)gng)[0] == 0x3F800000u;
}

#define P_DWW 0
#define P_CW 3200
#define P_CB 4736
#define P_GNG 5120
#define P_GNB 5248
#define P_PWW 5376
#define P_PWB 5504
#define P_DTB 5505
#define P_ALOG 5513
#define P_DSKIP 5521
#define P_NG 5529

__global__ void k_prep_params(const void* dww, const void* cw, const void* cb,
                              const void* gng, const void* gnb, const void* pww,
                              const void* pwb, const void* dtbias, const void* alog,
                              const void* dskip, const void* ng, float* __restrict__ P,
                              float* __restrict__ gst) {
  bool f = in_is_f32(gng);
  int tid = threadIdx.x;
  if (tid < 128) gst[tid] = 0.f;
  auto cvt = [&](const void* src, int n, int off) {
    for (int i = tid; i < n; i += 256)
      P[off + i] = f ? ((const float*)src)[i] : b2f(((const unsigned short*)src)[i]);
  };
  cvt(dww, 3200, P_DWW);
  cvt(cw, 1536, P_CW);
  cvt(cb, 384, P_CB);
  cvt(gng, 128, P_GNG);
  cvt(gnb, 128, P_GNB);
  cvt(pww, 128, P_PWW);
  cvt(pwb, 1, P_PWB);
  cvt(dtbias, 8, P_DTB);
  cvt(alog, 8, P_ALOG);
  cvt(dskip, 8, P_DSKIP);
  cvt(ng, 256, P_NG);
}

__global__ void k_prep_w(const void* wproj, const void* outw, const void* gng,
                         float* __restrict__ wprojf, float* __restrict__ outwf) {
  bool f = in_is_f32(gng);
  int stride = gridDim.x * blockDim.x;
  for (int i = blockIdx.x * blockDim.x + threadIdx.x; i < 82944; i += stride)
    wprojf[i] = f ? ((const float*)wproj)[i] : b2f(((const unsigned short*)wproj)[i]);
  for (int i = blockIdx.x * blockDim.x + threadIdx.x; i < 32768; i += stride)
    outwf[i] = f ? ((const float*)outw)[i] : b2f(((const unsigned short*)outw)[i]);
}

// ---------------- K1 v2: depthwise 5x5 conv + group stats ------------------------
// f32 tile, column-sliding walk with 5-slot output ring (compile-time indices).
template <int H0>
__device__ __forceinline__ void dw_col(const float* __restrict__ t,
                                       const float* __restrict__ w, int col,
                                       float* __restrict__ h1, size_t outbase,
                                       float& s, float& sq) {
  float acc[5] = {0.f, 0.f, 0.f, 0.f, 0.f};
#pragma unroll
  for (int u = 0; u < 5; ++u) {
    int r = H0 + u;
    const float* row = t + r * 136 + col + 2;
    float v0 = row[0], v1 = row[1], v2 = row[2], v3 = row[3], v4 = row[4];
#pragma unroll
    for (int ky = 0; ky <= u; ++ky) {
      int sl = (H0 + u + 5 - ky) % 5;
      acc[sl] += w[ky * 5 + 0] * v0 + w[ky * 5 + 1] * v1 + w[ky * 5 + 2] * v2 +
                 w[ky * 5 + 3] * v3 + w[ky * 5 + 4] * v4;
    }
    if (u == 4) {
      int sl = H0 % 5;
      float ov = acc[sl];
      h1[outbase + (size_t)H0 * 128 + col] = ov;
      s += ov; sq += ov * ov;
      acc[sl] = 0.f;
    }
  }
  for (int o = 1; o < 13; ++o) {
#pragma unroll
    for (int u = 0; u < 5; ++u) {
      int r = H0 + o * 5 + u;
      const float* row = t + r * 136 + col + 2;
      float v0 = row[0], v1 = row[1], v2 = row[2], v3 = row[3], v4 = row[4];
#pragma unroll
      for (int ky = 0; ky < 5; ++ky) {
        int sl = (H0 + u + 5 - ky) % 5;
        acc[sl] += w[ky * 5 + 0] * v0 + w[ky * 5 + 1] * v1 + w[ky * 5 + 2] * v2 +
                   w[ky * 5 + 3] * v3 + w[ky * 5 + 4] * v4;
      }
      int dy = r - 4;
      int sl = (H0 + u + 1) % 5;
      float ov = acc[sl];
      h1[outbase + (size_t)dy * 128 + col] = ov;
      s += ov; sq += ov * ov;
      acc[sl] = 0.f;
    }
  }
#pragma unroll
  for (int u = 0; u < 3; ++u) {
    int r = H0 + 65 + u;
    const float* row = t + r * 136 + col + 2;
    float v0 = row[0], v1 = row[1], v2 = row[2], v3 = row[3], v4 = row[4];
#pragma unroll
    for (int ky = 0; ky < 5; ++ky) {
      int sl = (H0 + u + 5 - ky) % 5;
      acc[sl] += w[ky * 5 + 0] * v0 + w[ky * 5 + 1] * v1 + w[ky * 5 + 2] * v2 +
                 w[ky * 5 + 3] * v3 + w[ky * 5 + 4] * v4;
    }
    int dy = r - 4;
    int sl = (H0 + u + 1) % 5;
    float ov = acc[sl];
    h1[outbase + (size_t)dy * 128 + col] = ov;
    s += ov; sq += ov * ov;
    acc[sl] = 0.f;
  }
}

__global__ __launch_bounds__(256) void k_dwconv_v2(const void* __restrict__ x,
                                                   const void* __restrict__ gng,
                                                   const float* __restrict__ P,
                                                   float* __restrict__ h1,
                                                   float* __restrict__ gst) {
  int bc = blockIdx.x;
  int b = bc >> 7, chan = bc & 127;
  bool f32x = in_is_f32(gng);
  __shared__ __align__(16) float t[132 * 136];  // 71,808 B
  __shared__ float red[8];
  for (int i = threadIdx.x; i < (132 * 136) / 4; i += 256)
    ((float4*)t)[i] = make_float4(0.f, 0.f, 0.f, 0.f);
  __syncthreads();
  const float* xf = (const float*)x + (size_t)bc * 16384;
  const unsigned short* xb = (const unsigned short*)x + (size_t)bc * 16384;
  for (int i = threadIdx.x; i < 4096; i += 256) {
    int dy = i >> 5, dc = (i & 31) * 4;
    float4 v;
    if (f32x) {
      v = *(const float4*)&xf[i * 4];
    } else {
      ushort4 r4 = *(const ushort4*)&xb[i * 4];
      v = make_float4(b2f(r4.x), b2f(r4.y), b2f(r4.z), b2f(r4.w));
    }
    *(float4*)&t[(dy + 2) * 136 + dc + 4] = v;
  }
  float w[25];
#pragma unroll
  for (int k = 0; k < 25; ++k) w[k] = P[P_DWW + chan * 25 + k];
  __syncthreads();
  int col = threadIdx.x & 127;
  float s = 0.f, sq = 0.f;
  size_t outbase = (size_t)bc * 16384;
  if (threadIdx.x < 128) dw_col<0>(t, w, col, h1, outbase, s, sq);
  else                   dw_col<64>(t, w, col, h1, outbase, s, sq);
  for (int o = 32; o; o >>= 1) { s += __shfl_down(s, o, 64); sq += __shfl_down(sq, o, 64); }
  int wv = threadIdx.x >> 6;
  if ((threadIdx.x & 63) == 0) { red[wv] = s; red[4 + wv] = sq; }
  __syncthreads();
  if (threadIdx.x == 0) {
    float ts = red[0] + red[1] + red[2] + red[3];
    float tq = red[4] + red[5] + red[6] + red[7];
    int g = (b << 3) + (chan >> 4);
    atomicAdd(&gst[g * 2], ts);
    atomicAdd(&gst[g * 2 + 1], tq);
  }
}

__global__ void k_stats(const float* __restrict__ gst, float* __restrict__ mr) {
  int g = threadIdx.x;
  if (g < 64) {
    const float invN = 1.f / 262144.f;
    float mean = gst[g * 2] * invN;
    float var = gst[g * 2 + 1] * invN - mean * mean;
    mr[g * 2] = mean;
    mr[g * 2 + 1] = rsqrtf(var + 1e-5f);
  }
}

// ---------------- K3: GN + exact GELU + 1x1 conv + tanh*8 -> offset (f32 out) ----
__global__ __launch_bounds__(128) void k_gn_off(const float* __restrict__ h1,
                                                const float* __restrict__ mr,
                                                const float* __restrict__ P,
                                                float* __restrict__ offf,
                                                float* __restrict__ dout) {
  int bh = blockIdx.x;
  int b = bh >> 7, h = bh & 127;
  int w = threadIdx.x;
  float acc = 0.f;
  for (int c = 0; c < 128; ++c) {
    float v = h1[(((size_t)(b * 128 + c)) * 128 + h) * 128 + w];
    int g = b * 8 + (c >> 4);
    float nv = (v - mr[g * 2]) * mr[g * 2 + 1] * P[P_GNG + c] + P[P_GNB + c];
    float ge = 0.5f * nv * (1.f + erff(nv * 0.70710678118f));
    acc += ge * P[P_PWW + c];
  }
  float off = acc + P[P_PWB];
  float ofv = tanhf(off) * 8.0f;
  offf[bh * 128 + w] = ofv;
  dout[16777216 + bh * 128 + w] = ofv;
}

// ---------------- K4 v2: grid sample + transpose, 256 threads --------------------
// thread = (w, half): staging splits c-range, write splits l-range. Stride 129
// keeps both phases conflict-free.
__global__ __launch_bounds__(256) void k_deform_v2(const void* __restrict__ x,
                                                   const void* __restrict__ gng,
                                                   const float* __restrict__ offf,
                                                   float* __restrict__ seqc,
                                                   int s0) {
  int bh = s0 + blockIdx.x;
  int b = bh >> 7, h = bh & 127;
  int w = threadIdx.x & 127;
  int half = threadIdx.x >> 7;  // 0..1
  bool f32x = in_is_f32(gng);
  __shared__ float t[128 * 129];
  float ofv = offf[bh * 128 + w];
  float gy = -1.f + (2.f / 127.f) * (float)h + ofv * (2.f / 127.f);
  gy = fminf(fmaxf(gy, -1.f), 1.f);
  float py = (gy + 1.f) * 0.5f * 127.f;
  py = fminf(fmaxf(py, 0.f), 127.f);
  float y0f = floorf(py);
  float wy = py - y0f;
  int y0 = (int)y0f;
  int y1 = min(y0 + 1, 127);
  const float* xfb = (const float*)x + (size_t)b * 128 * 16384;
  const unsigned short* xbb = (const unsigned short*)x + (size_t)b * 128 * 16384;
  for (int c = half * 64; c < half * 64 + 64; ++c) {
    size_t o0 = (size_t)c * 16384 + y0 * 128 + w;
    size_t o1 = (size_t)c * 16384 + y1 * 128 + w;
    float v0, v1;
    if (f32x) { v0 = xfb[o0]; v1 = xfb[o1]; }
    else      { v0 = b2f(xbb[o0]); v1 = b2f(xbb[o1]); }
    t[c * 129 + w] = v0 + wy * (v1 - v0);
  }
  __syncthreads();
  int c = threadIdx.x & 127;
  float* sp = seqc + (size_t)blockIdx.x * 16384;
  for (int l = half * 64; l < half * 64 + 64; ++l) sp[l * 128 + c] = t[c * 129 + l];
}

// ---------------- G1 v3: zxbcdt = seq @ wproj^T — 64x64 tile, 4x4/thread ---------
__global__ __launch_bounds__(256) void k_gemm1_v3(const float* __restrict__ seqp,
                                                  const float* __restrict__ wproj,
                                                  const float* __restrict__ P,
                                                  float* __restrict__ z,
                                                  float* __restrict__ xbc,
                                                  float* __restrict__ dtb) {
  __shared__ float As[32 * 68];  // [k][m], m-pad 64->68
  __shared__ float Bs[32 * 68];  // [k][e]
  int m0 = blockIdx.x * 64;
  int e0 = blockIdx.y * 64;      // 0..640; y=10 has tail (648)
  int tx = threadIdx.x & 15;     // e quad
  int ty = threadIdx.x >> 4;     // m quad
  float acc[4][4] = {};
  for (int kt = 0; kt < 128; kt += 32) {
    for (int i = threadIdx.x; i < 512; i += 256) {
      int m = i >> 3, k4 = (i & 7) * 4;
      float4 v = *(const float4*)&seqp[(size_t)(m0 + m) * 128 + kt + k4];
      As[(k4 + 0) * 68 + m] = v.x;
      As[(k4 + 1) * 68 + m] = v.y;
      As[(k4 + 2) * 68 + m] = v.z;
      As[(k4 + 3) * 68 + m] = v.w;
    }
    for (int i = threadIdx.x; i < 512; i += 256) {
      int e = i >> 3, k4 = (i & 7) * 4;
      float4 v = make_float4(0.f, 0.f, 0.f, 0.f);
      if (e0 + e < 648)
        v = *(const float4*)&wproj[(size_t)(e0 + e) * 128 + kt + k4];
      Bs[(k4 + 0) * 68 + e] = v.x;
      Bs[(k4 + 1) * 68 + e] = v.y;
      Bs[(k4 + 2) * 68 + e] = v.z;
      Bs[(k4 + 3) * 68 + e] = v.w;
    }
    __syncthreads();
#pragma unroll 8
    for (int k = 0; k < 32; ++k) {
      float4 a = *(const float4*)&As[k * 68 + ty * 4];
      float4 b = *(const float4*)&Bs[k * 68 + tx * 4];
      float av[4] = {a.x, a.y, a.z, a.w};
      float bv[4] = {b.x, b.y, b.z, b.w};
#pragma unroll
      for (int i = 0; i < 4; ++i)
#pragma unroll
        for (int j = 0; j < 4; ++j) acc[i][j] += av[i] * bv[j];
    }
    __syncthreads();
  }
#pragma unroll
  for (int i = 0; i < 4; ++i) {
    int m = m0 + ty * 4 + i;
#pragma unroll
    for (int j = 0; j < 4; ++j) {
      int e = e0 + tx * 4 + j;
      float v = acc[i][j];
      if (e < 256) {
        z[(size_t)m * 256 + e] = v;
      } else if (e < 640) {
        xbc[(size_t)m * 384 + (e - 256)] = v;
      } else if (e < 648) {
        float dv = v + P[P_DTB + e - 640];
        float sp = (dv > 20.f) ? dv : log1pf(__expf(dv));
        dtb[(size_t)m * 8 + (e - 640)] = sp;
      }
    }
  }
}

// ---------------- K5 v3: causal conv1d + SiLU, IN-PLACE --------------------------
// Each thread exclusively owns channel column e: reads xbc[l*384+e] before
// writing the same location -> in-place safe. Saves 196KB/seq workspace.
__global__ __launch_bounds__(256) void k_conv1d_v3(float* __restrict__ xbc,
                                                   const float* __restrict__ P) {
  float* buf = xbc + (size_t)blockIdx.x * 49152;   // 128*384
  for (int e = threadIdx.x; e < 384; e += 256) {
    float w0 = P[P_CW + e * 4 + 0], w1 = P[P_CW + e * 4 + 1];
    float w2 = P[P_CW + e * 4 + 2], w3 = P[P_CW + e * 4 + 3];
    float bb = P[P_CB + e];
    float x0 = 0.f, x1 = 0.f, x2 = 0.f;
    for (int l = 0; l < 128; ++l) {
      float x3 = buf[l * 384 + e];
      float a = bb + w0 * x0 + w1 * x1 + w2 * x2 + w3 * x3;
      buf[l * 384 + e] = a / (1.f + __expf(-a));
      x0 = x1; x1 = x2; x2 = x3;
    }
  }
}

// ---------------- K6 v4: selective scan — bulk LDS staging + float4 B/C ----------
// v3 was latency/issue bound at 4 waves/CU: 128 scalar ds_read_b32 per l (B,C)
// plus dependent global loads (xv, dt) in the serial loop. v4 stages the whole
// row block (x|B|C, 16 l x 384 f32 = 24KB) + dt in one coalesced float4 phase;
// inner loop reads B/C as float4 (32 ds_read_b128 per l) and xv/dt from LDS.
// acc split into 4 chains to shorten the serial FMA dependency.
__global__ __launch_bounds__(256) void k_scan_v4(const float* __restrict__ pc,
                                                 const float* __restrict__ dtb,
                                                 const float* __restrict__ P,
                                                 float* __restrict__ ys) {
  int seq = blockIdx.x;
  int head = threadIdx.x >> 5;    // 0..7
  float A = -__expf(P[P_ALOG + head]);
  float Dk = P[P_DSKIP + head];
  float h[64];
#pragma unroll
  for (int s = 0; s < 64; ++s) h[s] = 0.f;
  __shared__ __align__(16) float sROW[16][384];  // 24,576 B: x[0..255]|B|C
  __shared__ float sDT[16][8];
  const float* base = pc + (size_t)seq * 49152;
  const float* dtp = dtb + (size_t)seq * 1024;
  float* yp = ys + (size_t)seq * 32768;
  for (int lt = 0; lt < 128; lt += 16) {
    const float* gsrc = base + (size_t)lt * 384;
    for (int i = threadIdx.x; i < 1536; i += 256) {
      int ll = i / 96, c4 = i % 96;
      *(float4*)&sROW[ll][c4 * 4] = *(const float4*)&gsrc[ll * 384 + c4 * 4];
    }
    if (threadIdx.x < 128)
      sDT[threadIdx.x >> 3][threadIdx.x & 7] =
          dtp[(lt + (threadIdx.x >> 3)) * 8 + (threadIdx.x & 7)];
    __syncthreads();
#pragma unroll 1
    for (int ll = 0; ll < 16; ++ll) {
      float dt = sDT[ll][head];
      float dA = __expf(dt * A);
      float xv = sROW[ll][threadIdx.x];        // head*32+d == threadIdx.x
      float coef = dt * xv;
      float a0 = 0.f, a1 = 0.f, a2 = 0.f, a3 = 0.f;
#pragma unroll
      for (int s4 = 0; s4 < 16; ++s4) {
        float4 bb = *(const float4*)&sROW[ll][256 + s4 * 4];
        float4 cc = *(const float4*)&sROW[ll][320 + s4 * 4];
        h[4 * s4 + 0] = h[4 * s4 + 0] * dA + coef * bb.x; a0 += h[4 * s4 + 0] * cc.x;
        h[4 * s4 + 1] = h[4 * s4 + 1] * dA + coef * bb.y; a1 += h[4 * s4 + 1] * cc.y;
        h[4 * s4 + 2] = h[4 * s4 + 2] * dA + coef * bb.z; a2 += h[4 * s4 + 2] * cc.z;
        h[4 * s4 + 3] = h[4 * s4 + 3] * dA + coef * bb.w; a3 += h[4 * s4 + 3] * cc.w;
      }
      yp[(lt + ll) * 256 + threadIdx.x] = (a0 + a1) + (a2 + a3) + Dk * xv;
    }
    __syncthreads();
  }
}

// ---------------- K7 v3: gate + RMS norm, IN-PLACE (ynorm over ys) ---------------
__global__ __launch_bounds__(256) void k_gate_v3(float* __restrict__ ys,
                                                 const float* __restrict__ z,
                                                 const float* __restrict__ P) {
  int l = blockIdx.x;
  int e = threadIdx.x;
  __shared__ float red[4];
  float yv = ys[(size_t)l * 256 + e];
  float zv = z[(size_t)l * 256 + e];
  float g = zv / (1.f + __expf(-zv));
  float y = yv * g;
  float ss = y * y;
  for (int o = 32; o; o >>= 1) ss += __shfl_down(ss, o, 64);
  if ((threadIdx.x & 63) == 0) red[threadIdx.x >> 6] = ss;
  __syncthreads();
  float tot = red[0] + red[1] + red[2] + red[3];
  float r = rsqrtf(tot * (1.f / 256.f) + 1e-5f);
  ys[(size_t)l * 256 + e] = y * r * P[P_NG + e];
}

// ---------------- G2 v3: out GEMM — 64x64 tile, 4x4/thread, f32 NCHW store -------
__global__ __launch_bounds__(256) void k_gemm2_v3(const float* __restrict__ ynorm,
                                                  const float* __restrict__ outw,
                                                  float* __restrict__ dout,
                                                  int tok0) {
  __shared__ float As[32 * 68];  // [k][token]
  __shared__ float Bs[32 * 68];  // [k][c]
  int t0 = blockIdx.x * 64;
  int c0 = blockIdx.y * 64;      // 0 or 64
  int tx = threadIdx.x & 15;     // c quad
  int ty = threadIdx.x >> 4;     // token quad
  float acc[4][4] = {};
  for (int kt = 0; kt < 256; kt += 32) {
    for (int i = threadIdx.x; i < 512; i += 256) {
      int m = i >> 3, k4 = (i & 7) * 4;
      float4 v = *(const float4*)&ynorm[(size_t)(t0 + m) * 256 + kt + k4];
      As[(k4 + 0) * 68 + m] = v.x;
      As[(k4 + 1) * 68 + m] = v.y;
      As[(k4 + 2) * 68 + m] = v.z;
      As[(k4 + 3) * 68 + m] = v.w;
    }
    for (int i = threadIdx.x; i < 512; i += 256) {
      int e = i >> 3, k4 = (i & 7) * 4;
      float4 v = *(const float4*)&outw[(size_t)(c0 + e) * 256 + kt + k4];
      Bs[(k4 + 0) * 68 + e] = v.x;
      Bs[(k4 + 1) * 68 + e] = v.y;
      Bs[(k4 + 2) * 68 + e] = v.z;
      Bs[(k4 + 3) * 68 + e] = v.w;
    }
    __syncthreads();
#pragma unroll 8
    for (int k = 0; k < 32; ++k) {
      float4 a = *(const float4*)&As[k * 68 + ty * 4];
      float4 b = *(const float4*)&Bs[k * 68 + tx * 4];
      float av[4] = {a.x, a.y, a.z, a.w};
      float bv[4] = {b.x, b.y, b.z, b.w};
#pragma unroll
      for (int i = 0; i < 4; ++i)
#pragma unroll
        for (int j = 0; j < 4; ++j) acc[i][j] += av[i] * bv[j];
    }
    __syncthreads();
  }
#pragma unroll
  for (int i = 0; i < 4; ++i) {
    int l = tok0 + t0 + ty * 4 + i;
    int b = l >> 14, rem = l & 16383;
    int hh = rem >> 7, ww = rem & 127;
#pragma unroll
    for (int j = 0; j < 4; ++j) {
      int cc = c0 + tx * 4 + j;
      dout[(((size_t)(b * 128 + cc) * 128 + hh) * 128 + ww)] = acc[i][j];
    }
  }
}

extern "C" void kernel_launch(void* const* d_in, const int* in_sizes, int n_in,
                              void* d_out, int out_size, void* d_ws, size_t ws_size,
                              hipStream_t stream) {
  const void* x      = d_in[0];
  const void* dww    = d_in[1];
  const void* gng    = d_in[2];
  const void* gnb    = d_in[3];
  const void* pww    = d_in[4];
  const void* pwb    = d_in[5];
  const void* wproj  = d_in[6];
  const void* cw     = d_in[7];
  const void* cb     = d_in[8];
  const void* dtbias = d_in[9];
  const void* alog   = d_in[10];
  const void* dskip  = d_in[11];
  const void* ng     = d_in[12];
  const void* outw   = d_in[13];
  float* out = (float*)d_out;

  char* ws = (char*)d_ws;
  float* gst    = (float*)(ws + 0);
  float* mr     = (float*)(ws + 4096);
  float* P      = (float*)(ws + 8192);
  float* wprojf = (float*)(ws + 40960);
  float* outwf  = (float*)(ws + 372736);
  float* offf   = (float*)(ws + 503808);
  char* cbase   = ws + 1028096;

  // h1 (f32, 67,108,864 B) lives in d_out's out_2d region.
  float* h1f = out;

  // Per-sequence chunk bytes (in-place conv1d + gate):
  //   seq 65536 + z 131072 + xbc 196608 + dtb 4096 + ys 131072 = 528384.
  const int opts[11] = {1024, 512, 256, 128, 64, 32, 16, 8, 4, 2, 1};
  int CH = 1;
  for (int i = 0; i < 11; ++i) {
    if (1028096ull + (unsigned long long)opts[i] * 528384ull <= (unsigned long long)ws_size) {
      CH = opts[i];
      break;
    }
  }
  int NC = 1024 / CH;

  float* seqf = (float*)(cbase);
  float* zf   = (float*)(cbase + (size_t)CH * 65536);
  float* xbcf = (float*)(cbase + (size_t)CH * 196608);
  float* dtbf = (float*)(cbase + (size_t)CH * 393216);
  float* ysf  = (float*)(cbase + (size_t)CH * 397312);

  k_prep_params<<<1, 256, 0, stream>>>(dww, cw, cb, gng, gnb, pww, pwb, dtbias,
                                       alog, dskip, ng, P, gst);
  k_prep_w<<<128, 256, 0, stream>>>(wproj, outw, gng, wprojf, outwf);
  k_dwconv_v2<<<1024, 256, 0, stream>>>(x, gng, P, h1f, gst);
  k_stats<<<1, 64, 0, stream>>>(gst, mr);
  k_gn_off<<<1024, 128, 0, stream>>>(h1f, mr, P, offf, out);

  for (int c = 0; c < NC; ++c) {
    int s0 = c * CH;
    k_deform_v2<<<CH, 256, 0, stream>>>(x, gng, offf, seqf, s0);
    k_gemm1_v3<<<dim3(CH * 2, 11), 256, 0, stream>>>(seqf, wprojf, P, zf, xbcf, dtbf);
    k_conv1d_v3<<<CH, 256, 0, stream>>>(xbcf, P);
    k_scan_v4<<<CH, 256, 0, stream>>>(xbcf, dtbf, P, ysf);
    k_gate_v3<<<CH * 128, 256, 0, stream>>>(ysf, zf, P);
    k_gemm2_v3<<<dim3(CH * 2, 2), 256, 0, stream>>>(ysf, outwf, out, s0 * 128);
  }
}

// Round 6
// 1314.072 us; speedup vs baseline: 3.7444x; 1.2214x over previous
//
#include <hip/hip_runtime.h>
#include <math.h>

// B=8, C=128, H=128, W=128, D_INNER=256, D_STATE=64, HEADDIM=32, NHEADS=8,
// D_CONV=4, GN_GROUPS=8, D_XBC=384, D_INPROJ=648.
// Inputs f32 (probed via gn_g word0). OUTPUT IS F32 (reference output dtype).
// d_out = [out_2d: 16,777,216 f32][offset: 131,072 f32].
// h1 (f32) is staged in d_out's out_2d region.

__device__ __forceinline__ float b2f(unsigned short u) {
  return __uint_as_float(((unsigned int)u) << 16);
}
__device__ __forceinline__ bool in_is_f32(const void* gng) {
  return ((const unsigned int*)gng)[0] == 0x3F800000u;
}

// Sum over the 4-lane quad (lane&3 butterfly). DPP quad_perm keeps it on the
// VALU pipe (ds_bpermute would hit the LDS pipe we're trying to unload).
__device__ __forceinline__ float quad_sum(float v) {
#if __has_builtin(__builtin_amdgcn_update_dpp)
  int p = __builtin_amdgcn_update_dpp(0, __float_as_int(v), 0xB1, 0xF, 0xF, true);
  v += __int_as_float(p);  // xor 1 (quad_perm [1,0,3,2])
  p = __builtin_amdgcn_update_dpp(0, __float_as_int(v), 0x4E, 0xF, 0xF, true);
  v += __int_as_float(p);  // xor 2 (quad_perm [2,3,0,1])
#else
  v += __shfl_xor(v, 1, 64);
  v += __shfl_xor(v, 2, 64);
#endif
  return v;
}

#define P_DWW 0
#define P_CW 3200
#define P_CB 4736
#define P_GNG 5120
#define P_GNB 5248
#define P_PWW 5376
#define P_PWB 5504
#define P_DTB 5505
#define P_ALOG 5513
#define P_DSKIP 5521
#define P_NG 5529

__global__ void k_prep_params(const void* dww, const void* cw, const void* cb,
                              const void* gng, const void* gnb, const void* pww,
                              const void* pwb, const void* dtbias, const void* alog,
                              const void* dskip, const void* ng, float* __restrict__ P,
                              float* __restrict__ gst) {
  bool f = in_is_f32(gng);
  int tid = threadIdx.x;
  if (tid < 128) gst[tid] = 0.f;
  auto cvt = [&](const void* src, int n, int off) {
    for (int i = tid; i < n; i += 256)
      P[off + i] = f ? ((const float*)src)[i] : b2f(((const unsigned short*)src)[i]);
  };
  cvt(dww, 3200, P_DWW);
  cvt(cw, 1536, P_CW);
  cvt(cb, 384, P_CB);
  cvt(gng, 128, P_GNG);
  cvt(gnb, 128, P_GNB);
  cvt(pww, 128, P_PWW);
  cvt(pwb, 1, P_PWB);
  cvt(dtbias, 8, P_DTB);
  cvt(alog, 8, P_ALOG);
  cvt(dskip, 8, P_DSKIP);
  cvt(ng, 256, P_NG);
}

__global__ void k_prep_w(const void* wproj, const void* outw, const void* gng,
                         float* __restrict__ wprojf, float* __restrict__ outwf) {
  bool f = in_is_f32(gng);
  int stride = gridDim.x * blockDim.x;
  for (int i = blockIdx.x * blockDim.x + threadIdx.x; i < 82944; i += stride)
    wprojf[i] = f ? ((const float*)wproj)[i] : b2f(((const unsigned short*)wproj)[i]);
  for (int i = blockIdx.x * blockDim.x + threadIdx.x; i < 32768; i += stride)
    outwf[i] = f ? ((const float*)outw)[i] : b2f(((const unsigned short*)outw)[i]);
}

// ---------------- K1 v2: depthwise 5x5 conv + group stats ------------------------
// f32 tile, column-sliding walk with 5-slot output ring (compile-time indices).
template <int H0>
__device__ __forceinline__ void dw_col(const float* __restrict__ t,
                                       const float* __restrict__ w, int col,
                                       float* __restrict__ h1, size_t outbase,
                                       float& s, float& sq) {
  float acc[5] = {0.f, 0.f, 0.f, 0.f, 0.f};
#pragma unroll
  for (int u = 0; u < 5; ++u) {
    int r = H0 + u;
    const float* row = t + r * 136 + col + 2;
    float v0 = row[0], v1 = row[1], v2 = row[2], v3 = row[3], v4 = row[4];
#pragma unroll
    for (int ky = 0; ky <= u; ++ky) {
      int sl = (H0 + u + 5 - ky) % 5;
      acc[sl] += w[ky * 5 + 0] * v0 + w[ky * 5 + 1] * v1 + w[ky * 5 + 2] * v2 +
                 w[ky * 5 + 3] * v3 + w[ky * 5 + 4] * v4;
    }
    if (u == 4) {
      int sl = H0 % 5;
      float ov = acc[sl];
      h1[outbase + (size_t)H0 * 128 + col] = ov;
      s += ov; sq += ov * ov;
      acc[sl] = 0.f;
    }
  }
  for (int o = 1; o < 13; ++o) {
#pragma unroll
    for (int u = 0; u < 5; ++u) {
      int r = H0 + o * 5 + u;
      const float* row = t + r * 136 + col + 2;
      float v0 = row[0], v1 = row[1], v2 = row[2], v3 = row[3], v4 = row[4];
#pragma unroll
      for (int ky = 0; ky < 5; ++ky) {
        int sl = (H0 + u + 5 - ky) % 5;
        acc[sl] += w[ky * 5 + 0] * v0 + w[ky * 5 + 1] * v1 + w[ky * 5 + 2] * v2 +
                   w[ky * 5 + 3] * v3 + w[ky * 5 + 4] * v4;
      }
      int dy = r - 4;
      int sl = (H0 + u + 1) % 5;
      float ov = acc[sl];
      h1[outbase + (size_t)dy * 128 + col] = ov;
      s += ov; sq += ov * ov;
      acc[sl] = 0.f;
    }
  }
#pragma unroll
  for (int u = 0; u < 3; ++u) {
    int r = H0 + 65 + u;
    const float* row = t + r * 136 + col + 2;
    float v0 = row[0], v1 = row[1], v2 = row[2], v3 = row[3], v4 = row[4];
#pragma unroll
    for (int ky = 0; ky < 5; ++ky) {
      int sl = (H0 + u + 5 - ky) % 5;
      acc[sl] += w[ky * 5 + 0] * v0 + w[ky * 5 + 1] * v1 + w[ky * 5 + 2] * v2 +
                 w[ky * 5 + 3] * v3 + w[ky * 5 + 4] * v4;
    }
    int dy = r - 4;
    int sl = (H0 + u + 1) % 5;
    float ov = acc[sl];
    h1[outbase + (size_t)dy * 128 + col] = ov;
    s += ov; sq += ov * ov;
    acc[sl] = 0.f;
  }
}

__global__ __launch_bounds__(256) void k_dwconv_v2(const void* __restrict__ x,
                                                   const void* __restrict__ gng,
                                                   const float* __restrict__ P,
                                                   float* __restrict__ h1,
                                                   float* __restrict__ gst) {
  int bc = blockIdx.x;
  int b = bc >> 7, chan = bc & 127;
  bool f32x = in_is_f32(gng);
  __shared__ __align__(16) float t[132 * 136];  // 71,808 B
  __shared__ float red[8];
  for (int i = threadIdx.x; i < (132 * 136) / 4; i += 256)
    ((float4*)t)[i] = make_float4(0.f, 0.f, 0.f, 0.f);
  __syncthreads();
  const float* xf = (const float*)x + (size_t)bc * 16384;
  const unsigned short* xb = (const unsigned short*)x + (size_t)bc * 16384;
  for (int i = threadIdx.x; i < 4096; i += 256) {
    int dy = i >> 5, dc = (i & 31) * 4;
    float4 v;
    if (f32x) {
      v = *(const float4*)&xf[i * 4];
    } else {
      ushort4 r4 = *(const ushort4*)&xb[i * 4];
      v = make_float4(b2f(r4.x), b2f(r4.y), b2f(r4.z), b2f(r4.w));
    }
    *(float4*)&t[(dy + 2) * 136 + dc + 4] = v;
  }
  float w[25];
#pragma unroll
  for (int k = 0; k < 25; ++k) w[k] = P[P_DWW + chan * 25 + k];
  __syncthreads();
  int col = threadIdx.x & 127;
  float s = 0.f, sq = 0.f;
  size_t outbase = (size_t)bc * 16384;
  if (threadIdx.x < 128) dw_col<0>(t, w, col, h1, outbase, s, sq);
  else                   dw_col<64>(t, w, col, h1, outbase, s, sq);
  for (int o = 32; o; o >>= 1) { s += __shfl_down(s, o, 64); sq += __shfl_down(sq, o, 64); }
  int wv = threadIdx.x >> 6;
  if ((threadIdx.x & 63) == 0) { red[wv] = s; red[4 + wv] = sq; }
  __syncthreads();
  if (threadIdx.x == 0) {
    float ts = red[0] + red[1] + red[2] + red[3];
    float tq = red[4] + red[5] + red[6] + red[7];
    int g = (b << 3) + (chan >> 4);
    atomicAdd(&gst[g * 2], ts);
    atomicAdd(&gst[g * 2 + 1], tq);
  }
}

__global__ void k_stats(const float* __restrict__ gst, float* __restrict__ mr) {
  int g = threadIdx.x;
  if (g < 64) {
    const float invN = 1.f / 262144.f;
    float mean = gst[g * 2] * invN;
    float var = gst[g * 2 + 1] * invN - mean * mean;
    mr[g * 2] = mean;
    mr[g * 2 + 1] = rsqrtf(var + 1e-5f);
  }
}

// ---------------- K3: GN + exact GELU + 1x1 conv + tanh*8 -> offset (f32 out) ----
__global__ __launch_bounds__(128) void k_gn_off(const float* __restrict__ h1,
                                                const float* __restrict__ mr,
                                                const float* __restrict__ P,
                                                float* __restrict__ offf,
                                                float* __restrict__ dout) {
  int bh = blockIdx.x;
  int b = bh >> 7, h = bh & 127;
  int w = threadIdx.x;
  float acc = 0.f;
  for (int c = 0; c < 128; ++c) {
    float v = h1[(((size_t)(b * 128 + c)) * 128 + h) * 128 + w];
    int g = b * 8 + (c >> 4);
    float nv = (v - mr[g * 2]) * mr[g * 2 + 1] * P[P_GNG + c] + P[P_GNB + c];
    float ge = 0.5f * nv * (1.f + erff(nv * 0.70710678118f));
    acc += ge * P[P_PWW + c];
  }
  float off = acc + P[P_PWB];
  float ofv = tanhf(off) * 8.0f;
  offf[bh * 128 + w] = ofv;
  dout[16777216 + bh * 128 + w] = ofv;
}

// ---------------- K4 v2: grid sample + transpose, 256 threads --------------------
__global__ __launch_bounds__(256) void k_deform_v2(const void* __restrict__ x,
                                                   const void* __restrict__ gng,
                                                   const float* __restrict__ offf,
                                                   float* __restrict__ seqc,
                                                   int s0) {
  int bh = s0 + blockIdx.x;
  int b = bh >> 7, h = bh & 127;
  int w = threadIdx.x & 127;
  int half = threadIdx.x >> 7;  // 0..1
  bool f32x = in_is_f32(gng);
  __shared__ float t[128 * 129];
  float ofv = offf[bh * 128 + w];
  float gy = -1.f + (2.f / 127.f) * (float)h + ofv * (2.f / 127.f);
  gy = fminf(fmaxf(gy, -1.f), 1.f);
  float py = (gy + 1.f) * 0.5f * 127.f;
  py = fminf(fmaxf(py, 0.f), 127.f);
  float y0f = floorf(py);
  float wy = py - y0f;
  int y0 = (int)y0f;
  int y1 = min(y0 + 1, 127);
  const float* xfb = (const float*)x + (size_t)b * 128 * 16384;
  const unsigned short* xbb = (const unsigned short*)x + (size_t)b * 128 * 16384;
  for (int c = half * 64; c < half * 64 + 64; ++c) {
    size_t o0 = (size_t)c * 16384 + y0 * 128 + w;
    size_t o1 = (size_t)c * 16384 + y1 * 128 + w;
    float v0, v1;
    if (f32x) { v0 = xfb[o0]; v1 = xfb[o1]; }
    else      { v0 = b2f(xbb[o0]); v1 = b2f(xbb[o1]); }
    t[c * 129 + w] = v0 + wy * (v1 - v0);
  }
  __syncthreads();
  int c = threadIdx.x & 127;
  float* sp = seqc + (size_t)blockIdx.x * 16384;
  for (int l = half * 64; l < half * 64 + 64; ++l) sp[l * 128 + c] = t[c * 129 + l];
}

// ---------------- G1 v3: zxbcdt = seq @ wproj^T — 64x64 tile, 4x4/thread ---------
__global__ __launch_bounds__(256) void k_gemm1_v3(const float* __restrict__ seqp,
                                                  const float* __restrict__ wproj,
                                                  const float* __restrict__ P,
                                                  float* __restrict__ z,
                                                  float* __restrict__ xbc,
                                                  float* __restrict__ dtb) {
  __shared__ float As[32 * 68];  // [k][m], m-pad 64->68
  __shared__ float Bs[32 * 68];  // [k][e]
  int m0 = blockIdx.x * 64;
  int e0 = blockIdx.y * 64;      // 0..640; y=10 has tail (648)
  int tx = threadIdx.x & 15;     // e quad
  int ty = threadIdx.x >> 4;     // m quad
  float acc[4][4] = {};
  for (int kt = 0; kt < 128; kt += 32) {
    for (int i = threadIdx.x; i < 512; i += 256) {
      int m = i >> 3, k4 = (i & 7) * 4;
      float4 v = *(const float4*)&seqp[(size_t)(m0 + m) * 128 + kt + k4];
      As[(k4 + 0) * 68 + m] = v.x;
      As[(k4 + 1) * 68 + m] = v.y;
      As[(k4 + 2) * 68 + m] = v.z;
      As[(k4 + 3) * 68 + m] = v.w;
    }
    for (int i = threadIdx.x; i < 512; i += 256) {
      int e = i >> 3, k4 = (i & 7) * 4;
      float4 v = make_float4(0.f, 0.f, 0.f, 0.f);
      if (e0 + e < 648)
        v = *(const float4*)&wproj[(size_t)(e0 + e) * 128 + kt + k4];
      Bs[(k4 + 0) * 68 + e] = v.x;
      Bs[(k4 + 1) * 68 + e] = v.y;
      Bs[(k4 + 2) * 68 + e] = v.z;
      Bs[(k4 + 3) * 68 + e] = v.w;
    }
    __syncthreads();
#pragma unroll 8
    for (int k = 0; k < 32; ++k) {
      float4 a = *(const float4*)&As[k * 68 + ty * 4];
      float4 b = *(const float4*)&Bs[k * 68 + tx * 4];
      float av[4] = {a.x, a.y, a.z, a.w};
      float bv[4] = {b.x, b.y, b.z, b.w};
#pragma unroll
      for (int i = 0; i < 4; ++i)
#pragma unroll
        for (int j = 0; j < 4; ++j) acc[i][j] += av[i] * bv[j];
    }
    __syncthreads();
  }
#pragma unroll
  for (int i = 0; i < 4; ++i) {
    int m = m0 + ty * 4 + i;
#pragma unroll
    for (int j = 0; j < 4; ++j) {
      int e = e0 + tx * 4 + j;
      float v = acc[i][j];
      if (e < 256) {
        z[(size_t)m * 256 + e] = v;
      } else if (e < 640) {
        xbc[(size_t)m * 384 + (e - 256)] = v;
      } else if (e < 648) {
        float dv = v + P[P_DTB + e - 640];
        float sp = (dv > 20.f) ? dv : log1pf(__expf(dv));
        dtb[(size_t)m * 8 + (e - 640)] = sp;
      }
    }
  }
}

// ---------------- K5 v3: causal conv1d + SiLU, IN-PLACE --------------------------
__global__ __launch_bounds__(256) void k_conv1d_v3(float* __restrict__ xbc,
                                                   const float* __restrict__ P) {
  float* buf = xbc + (size_t)blockIdx.x * 49152;   // 128*384
  for (int e = threadIdx.x; e < 384; e += 256) {
    float w0 = P[P_CW + e * 4 + 0], w1 = P[P_CW + e * 4 + 1];
    float w2 = P[P_CW + e * 4 + 2], w3 = P[P_CW + e * 4 + 3];
    float bb = P[P_CB + e];
    float x0 = 0.f, x1 = 0.f, x2 = 0.f;
    for (int l = 0; l < 128; ++l) {
      float x3 = buf[l * 384 + e];
      float a = bb + w0 * x0 + w1 * x1 + w2 * x2 + w3 * x3;
      buf[l * 384 + e] = a / (1.f + __expf(-a));
      x0 = x1; x1 = x2; x2 = x3;
    }
  }
}

// ---------------- K6 v5: selective scan — (d,s)-split, 512 threads ---------------
// v4 was stuck at 145us: (1) h[64]/thread exceeds arch VGPRs (VGPR_Count=48) ->
// AGPR-backed state, ~3x VALU inflation (VALUBusy 33% vs ~10% useful); (2) 32
// ds_read_b128 per l per wave on the shared LDS pipe at 1 wave/SIMD.
// v5: wave = one head; thread owns 2 d x 16 s = 32 states (register-resident).
// Per l per thread: 4 bb + 4 cc b128 + 1 xv b64 + 1 dt = 10 LDS ops (vs 32).
// s-partials reduced over the lane quad via DPP (VALU pipe). 8 waves/CU.
__global__ __launch_bounds__(512) void k_scan_v5(const float* __restrict__ pc,
                                                 const float* __restrict__ dtb,
                                                 const float* __restrict__ P,
                                                 float* __restrict__ ys) {
  int seq = blockIdx.x;
  int head = threadIdx.x >> 6;          // 0..7 (one wave per head)
  int dduo = (threadIdx.x >> 2) & 15;   // d = dduo*2 + {0,1}
  int squad = threadIdx.x & 3;          // s-range squad*16 .. +15
  float A = -__expf(P[P_ALOG + head]);
  float Dk = P[P_DSKIP + head];
  float h0[16], h1[16];
#pragma unroll
  for (int s = 0; s < 16; ++s) { h0[s] = 0.f; h1[s] = 0.f; }
  __shared__ __align__(16) float sROW[16][384];  // x[0..255] | B[256..319] | C[320..383]
  __shared__ float sDT[16][8];
  const float* base = pc + (size_t)seq * 49152;
  const float* dtp = dtb + (size_t)seq * 1024;
  float* yp = ys + (size_t)seq * 32768;
  const int sbase = 256 + squad * 16;
  const int cbase = sbase + 64;
  for (int lt = 0; lt < 128; lt += 16) {
    const float* gsrc = base + (size_t)lt * 384;
    for (int i = threadIdx.x; i < 1536; i += 512) {
      int ll = i / 96, c4 = i % 96;
      *(float4*)&sROW[ll][c4 * 4] = *(const float4*)&gsrc[ll * 384 + c4 * 4];
    }
    if (threadIdx.x < 128)
      sDT[threadIdx.x >> 3][threadIdx.x & 7] =
          dtp[(lt + (threadIdx.x >> 3)) * 8 + (threadIdx.x & 7)];
    __syncthreads();
#pragma unroll 1
    for (int ll = 0; ll < 16; ++ll) {
      float dt = sDT[ll][head];
      float dA = __expf(dt * A);
      float2 xv = *(const float2*)&sROW[ll][head * 32 + dduo * 2];
      float c0 = dt * xv.x, c1 = dt * xv.y;
      float a0 = 0.f, b0 = 0.f, a1 = 0.f, b1 = 0.f;
#pragma unroll
      for (int s4 = 0; s4 < 4; ++s4) {
        float4 bb = *(const float4*)&sROW[ll][sbase + s4 * 4];
        float4 cc = *(const float4*)&sROW[ll][cbase + s4 * 4];
        h0[s4 * 4 + 0] = h0[s4 * 4 + 0] * dA + c0 * bb.x; a0 += h0[s4 * 4 + 0] * cc.x;
        h0[s4 * 4 + 1] = h0[s4 * 4 + 1] * dA + c0 * bb.y; b0 += h0[s4 * 4 + 1] * cc.y;
        h0[s4 * 4 + 2] = h0[s4 * 4 + 2] * dA + c0 * bb.z; a0 += h0[s4 * 4 + 2] * cc.z;
        h0[s4 * 4 + 3] = h0[s4 * 4 + 3] * dA + c0 * bb.w; b0 += h0[s4 * 4 + 3] * cc.w;
        h1[s4 * 4 + 0] = h1[s4 * 4 + 0] * dA + c1 * bb.x; a1 += h1[s4 * 4 + 0] * cc.x;
        h1[s4 * 4 + 1] = h1[s4 * 4 + 1] * dA + c1 * bb.y; b1 += h1[s4 * 4 + 1] * cc.y;
        h1[s4 * 4 + 2] = h1[s4 * 4 + 2] * dA + c1 * bb.z; a1 += h1[s4 * 4 + 2] * cc.z;
        h1[s4 * 4 + 3] = h1[s4 * 4 + 3] * dA + c1 * bb.w; b1 += h1[s4 * 4 + 3] * cc.w;
      }
      float y0 = quad_sum(a0 + b0);
      float y1 = quad_sum(a1 + b1);
      if (squad == 0) {
        float2 o = make_float2(y0 + Dk * xv.x, y1 + Dk * xv.y);
        *(float2*)&yp[(size_t)(lt + ll) * 256 + head * 32 + dduo * 2] = o;
      }
    }
    __syncthreads();
  }
}

// ---------------- K7 v3: gate + RMS norm, IN-PLACE (ynorm over ys) ---------------
__global__ __launch_bounds__(256) void k_gate_v3(float* __restrict__ ys,
                                                 const float* __restrict__ z,
                                                 const float* __restrict__ P) {
  int l = blockIdx.x;
  int e = threadIdx.x;
  __shared__ float red[4];
  float yv = ys[(size_t)l * 256 + e];
  float zv = z[(size_t)l * 256 + e];
  float g = zv / (1.f + __expf(-zv));
  float y = yv * g;
  float ss = y * y;
  for (int o = 32; o; o >>= 1) ss += __shfl_down(ss, o, 64);
  if ((threadIdx.x & 63) == 0) red[threadIdx.x >> 6] = ss;
  __syncthreads();
  float tot = red[0] + red[1] + red[2] + red[3];
  float r = rsqrtf(tot * (1.f / 256.f) + 1e-5f);
  ys[(size_t)l * 256 + e] = y * r * P[P_NG + e];
}

// ---------------- G2 v3: out GEMM — 64x64 tile, 4x4/thread, f32 NCHW store -------
__global__ __launch_bounds__(256) void k_gemm2_v3(const float* __restrict__ ynorm,
                                                  const float* __restrict__ outw,
                                                  float* __restrict__ dout,
                                                  int tok0) {
  __shared__ float As[32 * 68];  // [k][token]
  __shared__ float Bs[32 * 68];  // [k][c]
  int t0 = blockIdx.x * 64;
  int c0 = blockIdx.y * 64;      // 0 or 64
  int tx = threadIdx.x & 15;     // c quad
  int ty = threadIdx.x >> 4;     // token quad
  float acc[4][4] = {};
  for (int kt = 0; kt < 256; kt += 32) {
    for (int i = threadIdx.x; i < 512; i += 256) {
      int m = i >> 3, k4 = (i & 7) * 4;
      float4 v = *(const float4*)&ynorm[(size_t)(t0 + m) * 256 + kt + k4];
      As[(k4 + 0) * 68 + m] = v.x;
      As[(k4 + 1) * 68 + m] = v.y;
      As[(k4 + 2) * 68 + m] = v.z;
      As[(k4 + 3) * 68 + m] = v.w;
    }
    for (int i = threadIdx.x; i < 512; i += 256) {
      int e = i >> 3, k4 = (i & 7) * 4;
      float4 v = *(const float4*)&outw[(size_t)(c0 + e) * 256 + kt + k4];
      Bs[(k4 + 0) * 68 + e] = v.x;
      Bs[(k4 + 1) * 68 + e] = v.y;
      Bs[(k4 + 2) * 68 + e] = v.z;
      Bs[(k4 + 3) * 68 + e] = v.w;
    }
    __syncthreads();
#pragma unroll 8
    for (int k = 0; k < 32; ++k) {
      float4 a = *(const float4*)&As[k * 68 + ty * 4];
      float4 b = *(const float4*)&Bs[k * 68 + tx * 4];
      float av[4] = {a.x, a.y, a.z, a.w};
      float bv[4] = {b.x, b.y, b.z, b.w};
#pragma unroll
      for (int i = 0; i < 4; ++i)
#pragma unroll
        for (int j = 0; j < 4; ++j) acc[i][j] += av[i] * bv[j];
    }
    __syncthreads();
  }
#pragma unroll
  for (int i = 0; i < 4; ++i) {
    int l = tok0 + t0 + ty * 4 + i;
    int b = l >> 14, rem = l & 16383;
    int hh = rem >> 7, ww = rem & 127;
#pragma unroll
    for (int j = 0; j < 4; ++j) {
      int cc = c0 + tx * 4 + j;
      dout[(((size_t)(b * 128 + cc) * 128 + hh) * 128 + ww)] = acc[i][j];
    }
  }
}

extern "C" void kernel_launch(void* const* d_in, const int* in_sizes, int n_in,
                              void* d_out, int out_size, void* d_ws, size_t ws_size,
                              hipStream_t stream) {
  const void* x      = d_in[0];
  const void* dww    = d_in[1];
  const void* gng    = d_in[2];
  const void* gnb    = d_in[3];
  const void* pww    = d_in[4];
  const void* pwb    = d_in[5];
  const void* wproj  = d_in[6];
  const void* cw     = d_in[7];
  const void* cb     = d_in[8];
  const void* dtbias = d_in[9];
  const void* alog   = d_in[10];
  const void* dskip  = d_in[11];
  const void* ng     = d_in[12];
  const void* outw   = d_in[13];
  float* out = (float*)d_out;

  char* ws = (char*)d_ws;
  float* gst    = (float*)(ws + 0);
  float* mr     = (float*)(ws + 4096);
  float* P      = (float*)(ws + 8192);
  float* wprojf = (float*)(ws + 40960);
  float* outwf  = (float*)(ws + 372736);
  float* offf   = (float*)(ws + 503808);
  char* cbase   = ws + 1028096;

  // h1 (f32, 67,108,864 B) lives in d_out's out_2d region.
  float* h1f = out;

  // Per-sequence chunk bytes (in-place conv1d + gate):
  //   seq 65536 + z 131072 + xbc 196608 + dtb 4096 + ys 131072 = 528384.
  const int opts[11] = {1024, 512, 256, 128, 64, 32, 16, 8, 4, 2, 1};
  int CH = 1;
  for (int i = 0; i < 11; ++i) {
    if (1028096ull + (unsigned long long)opts[i] * 528384ull <= (unsigned long long)ws_size) {
      CH = opts[i];
      break;
    }
  }
  int NC = 1024 / CH;

  float* seqf = (float*)(cbase);
  float* zf   = (float*)(cbase + (size_t)CH * 65536);
  float* xbcf = (float*)(cbase + (size_t)CH * 196608);
  float* dtbf = (float*)(cbase + (size_t)CH * 393216);
  float* ysf  = (float*)(cbase + (size_t)CH * 397312);

  k_prep_params<<<1, 256, 0, stream>>>(dww, cw, cb, gng, gnb, pww, pwb, dtbias,
                                       alog, dskip, ng, P, gst);
  k_prep_w<<<128, 256, 0, stream>>>(wproj, outw, gng, wprojf, outwf);
  k_dwconv_v2<<<1024, 256, 0, stream>>>(x, gng, P, h1f, gst);
  k_stats<<<1, 64, 0, stream>>>(gst, mr);
  k_gn_off<<<1024, 128, 0, stream>>>(h1f, mr, P, offf, out);

  for (int c = 0; c < NC; ++c) {
    int s0 = c * CH;
    k_deform_v2<<<CH, 256, 0, stream>>>(x, gng, offf, seqf, s0);
    k_gemm1_v3<<<dim3(CH * 2, 11), 256, 0, stream>>>(seqf, wprojf, P, zf, xbcf, dtbf);
    k_conv1d_v3<<<CH, 256, 0, stream>>>(xbcf, P);
    k_scan_v5<<<CH, 512, 0, stream>>>(xbcf, dtbf, P, ysf);
    k_gate_v3<<<CH * 128, 256, 0, stream>>>(ysf, zf, P);
    k_gemm2_v3<<<dim3(CH * 2, 2), 256, 0, stream>>>(ysf, outwf, out, s0 * 128);
  }
}